// Round 1
// baseline (805.740 us; speedup 1.0000x reference)
//
#include <hip/hip_runtime.h>
#include <cstdint>
#include <cstddef>

// Problem constants (fixed by the reference).
constexpr int kN = 50000;      // nodes
constexpr int kE = 800000;     // edges
constexpr int kG = 512;        // graphs
constexpr int kEdgeDim = 8;
constexpr float kNegSlope = 0.2f;

// ---------------------------------------------------------------------------
// CSR build: histogram of dst -> exclusive scan -> scatter (edge ids + attrs
// reordered into CSR order so the hot per-node loops read contiguously).
// ---------------------------------------------------------------------------
__global__ void k_hist(const int* __restrict__ dst, int* __restrict__ counts, int n) {
  int i = blockIdx.x * blockDim.x + threadIdx.x;
  if (i < n) atomicAdd(&counts[dst[i]], 1);
}

__global__ __launch_bounds__(1024) void k_scan(const int* __restrict__ counts,
                                               int* __restrict__ row_ptr, int n) {
  constexpr int T = 1024;
  __shared__ int sh[T];
  int tid = threadIdx.x;
  int chunk = (n + 1 + T - 1) / T;
  int start = tid * chunk;
  int local = 0;
  int csum_end = min(start + chunk, n);
  for (int j = start; j < csum_end; ++j) local += counts[j];
  sh[tid] = local;
  __syncthreads();
  // Hillis-Steele inclusive scan over the 1024 partials.
  for (int off = 1; off < T; off <<= 1) {
    int v = 0;
    if (tid >= off) v = sh[tid - off];
    __syncthreads();
    if (tid >= off) sh[tid] += v;
    __syncthreads();
  }
  int base = (tid > 0) ? sh[tid - 1] : 0;
  int end = min(start + chunk, n + 1);
  for (int j = start; j < end; ++j) {
    row_ptr[j] = base;
    if (j < n) base += counts[j];
  }
}

__global__ void k_scatter(const int* __restrict__ src, const int* __restrict__ dst,
                          const float* __restrict__ eattr,
                          const int* __restrict__ row_ptr, int* __restrict__ fill,
                          int* __restrict__ csr_src, float* __restrict__ csr_ea, int n) {
  int i = blockIdx.x * blockDim.x + threadIdx.x;
  if (i >= n) return;
  int d = dst[i];
  int p = row_ptr[d] + atomicAdd(&fill[d], 1);
  csr_src[p] = src[i];
  const float4* s4 = (const float4*)eattr + (size_t)i * 2;
  float4* d4 = (float4*)csr_ea + (size_t)p * 2;
  d4[0] = s4[0];
  d4[1] = s4[1];
}

// ---------------------------------------------------------------------------
// Node transform: xs = h@Ws + bs ; xd = h@Wd + bd.  Block = 128 threads,
// 16 nodes per block staged in LDS; each thread owns one output column
// (OUTD=128) or one column for 1/4 of the nodes (OUTD=32).
// ---------------------------------------------------------------------------
template <int IND, int OUTD>
__global__ __launch_bounds__(128) void k_transform(
    const float* __restrict__ h, const float* __restrict__ Ws, const float* __restrict__ bs,
    const float* __restrict__ Wd, const float* __restrict__ bd,
    float* __restrict__ xs, float* __restrict__ xd, int n_nodes) {
  constexpr int NPB = 16;            // nodes per block (50000 % 16 == 0)
  constexpr int GROUPS = 128 / OUTD; // 1 (OUTD=128) or 4 (OUTD=32)
  constexpr int NPT = NPB / GROUPS;  // nodes per thread
  __shared__ float sh[NPB][IND];
  int tid = threadIdx.x;
  int nb = blockIdx.x * NPB;
  for (int i = tid; i < NPB * IND; i += 128) {
    sh[i / IND][i % IND] = h[(size_t)(nb + i / IND) * IND + (i % IND)];
  }
  __syncthreads();
  int col = tid % OUTD;
  int g = tid / OUTD;
  float accs[NPT], accd[NPT];
  float bsv = bs[col], bdv = bd[col];
#pragma unroll
  for (int m = 0; m < NPT; ++m) { accs[m] = bsv; accd[m] = bdv; }
  for (int k = 0; k < IND; k += 2) {
    float ws0 = Ws[(size_t)k * OUTD + col], ws1 = Ws[(size_t)(k + 1) * OUTD + col];
    float wd0 = Wd[(size_t)k * OUTD + col], wd1 = Wd[(size_t)(k + 1) * OUTD + col];
#pragma unroll
    for (int m = 0; m < NPT; ++m) {
      float2 hv = *(const float2*)&sh[g * NPT + m][k];  // LDS broadcast, b64
      accs[m] += hv.x * ws0 + hv.y * ws1;
      accd[m] += hv.x * wd0 + hv.y * wd1;
    }
  }
#pragma unroll
  for (int m = 0; m < NPT; ++m) {
    int node = nb + g * NPT + m;
    if (node < n_nodes) {
      xs[(size_t)node * OUTD + col] = accs[m];
      xd[(size_t)node * OUTD + col] = accd[m];
    }
  }
}

// ---------------------------------------------------------------------------
// Fused GATv2 layer over CSR: one wave per destination node, online softmax.
// D=128,H=4: 2 channels/lane (ch = 2*lane); head = lane/16; score reduction
// is a 16-lane xor-shuffle tree.  D=32,H=1: lanes 32-63 mirror lanes 0-31.
// ---------------------------------------------------------------------------
template <int D, int H, bool DO_ELU>
__global__ __launch_bounds__(256) void k_gat(
    const int* __restrict__ row_ptr, const int* __restrict__ csr_src,
    const float* __restrict__ csr_ea,
    const float* __restrict__ xs, const float* __restrict__ xd,
    const float* __restrict__ att, const float* __restrict__ bias,
    const float* __restrict__ We, float* __restrict__ hout, int n_nodes) {
  constexpr int C = D / H;                  // channels per head (32)
  constexpr int CPL = (D > 64) ? D / 64 : 1; // channels per lane
  constexpr int GROUP = C / CPL;            // lanes sharing a head
  int lane = threadIdx.x & 63;
  int node = blockIdx.x * (blockDim.x >> 6) + (threadIdx.x >> 6);
  if (node >= n_nodes) return;
  int ch0 = (CPL > 1) ? lane * CPL : (lane & (D - 1));

  float xdv[CPL], attv[CPL], bv[CPL], wev[kEdgeDim][CPL];
#pragma unroll
  for (int j = 0; j < CPL; ++j) {
    xdv[j] = xd[(size_t)node * D + ch0 + j];
    attv[j] = att[ch0 + j];
    bv[j] = bias[ch0 + j];
  }
#pragma unroll
  for (int k = 0; k < kEdgeDim; ++k)
#pragma unroll
    for (int j = 0; j < CPL; ++j) wev[k][j] = We[k * D + ch0 + j];

  float m_run = -INFINITY, l_run = 0.f;
  float acc[CPL];
#pragma unroll
  for (int j = 0; j < CPL; ++j) acc[j] = 0.f;

  int beg = row_ptr[node], end = row_ptr[node + 1];
  for (int e = beg; e < end; ++e) {
    int s = csr_src[e];
    float xsv[CPL];
    if (CPL == 2) {
      float2 xv = ((const float2*)(xs + (size_t)s * D))[lane];
      xsv[0] = xv.x;
      xsv[1] = xv.y;
    } else {
      xsv[0] = xs[(size_t)s * D + ch0];
    }
    const float4* ea4 = (const float4*)(csr_ea + (size_t)e * 8);
    float4 a0 = ea4[0];
    float4 a1 = ea4[1];
    float sc = 0.f;
#pragma unroll
    for (int j = 0; j < CPL; ++j) {
      float ea = a0.x * wev[0][j] + a0.y * wev[1][j] + a0.z * wev[2][j] + a0.w * wev[3][j] +
                 a1.x * wev[4][j] + a1.y * wev[5][j] + a1.z * wev[6][j] + a1.w * wev[7][j];
      float z = xsv[j] + xdv[j] + ea;
      z = (z >= 0.f) ? z : kNegSlope * z;
      sc += z * attv[j];
    }
#pragma unroll
    for (int off = 1; off < GROUP; off <<= 1) sc += __shfl_xor(sc, off, 64);
    // online softmax update
    float newm = fmaxf(m_run, sc);
    float p = __expf(sc - newm);
    float scale = __expf(m_run - newm);  // 0 on first edge (m_run = -inf)
    l_run = l_run * scale + p;
#pragma unroll
    for (int j = 0; j < CPL; ++j) acc[j] = acc[j] * scale + p * xsv[j];
    m_run = newm;
  }

  float inv = (l_run > 0.f) ? (1.f / l_run) : 0.f;  // isolated node -> bias only
  if (CPL > 1 || lane < 32) {
#pragma unroll
    for (int j = 0; j < CPL; ++j) {
      float o = acc[j] * inv + bv[j];
      if (DO_ELU) o = (o > 0.f) ? o : (__expf(o) - 1.f);
      hout[(size_t)node * D + ch0 + j] = o;
    }
  }
}

// ---------------------------------------------------------------------------
// Global mean-pool (batch is sorted -> binary-search ranges) + 2-layer MLP.
// One wave per graph.
// ---------------------------------------------------------------------------
__device__ inline int lowerb(const int* a, int n, int v) {
  int lo = 0, hi = n;
  while (lo < hi) {
    int mid = (lo + hi) >> 1;
    if (a[mid] < v) lo = mid + 1; else hi = mid;
  }
  return lo;
}

__global__ __launch_bounds__(64) void k_pool_mlp(
    const float* __restrict__ h3, const int* __restrict__ batch,
    const float* __restrict__ Wm1, const float* __restrict__ bm1,
    const float* __restrict__ Wm2, const float* __restrict__ bm2,
    float* __restrict__ out, int n_nodes) {
  int g = blockIdx.x;
  int t = threadIdx.x;
  int lo = lowerb(batch, n_nodes, g);
  int hi = lowerb(batch, n_nodes, g + 1);
  int c = t & 31, half = t >> 5;
  float sum = 0.f;
  for (int i = lo + half; i < hi; i += 2) sum += h3[(size_t)i * 32 + c];
  sum += __shfl_xor(sum, 32, 64);
  float cnt = (float)(hi - lo);
  float emb = sum / fmaxf(cnt, 1.f);
  __shared__ float sh_emb[32];
  __shared__ float sh_hid[64];
  if (half == 0) sh_emb[c] = emb;
  __syncthreads();
  float hv = bm1[t];
  for (int k = 0; k < 32; ++k) hv += sh_emb[k] * Wm1[k * 64 + t];
  hv = fmaxf(hv, 0.f);
  sh_hid[t] = hv;
  __syncthreads();
  float ov = bm2[t];
  for (int k = 0; k < 64; ++k) ov += sh_hid[k] * Wm2[k * 64 + t];
  out[(size_t)g * 64 + t] = ov;
}

// ---------------------------------------------------------------------------
extern "C" void kernel_launch(void* const* d_in, const int* in_sizes, int n_in,
                              void* d_out, int out_size, void* d_ws, size_t ws_size,
                              hipStream_t stream) {
  const float* x = (const float*)d_in[0];
  const int* esrc = (const int*)d_in[1];
  const int* edst = (const int*)d_in[2];
  const float* eattr = (const float*)d_in[3];
  const int* batch = (const int*)d_in[4];
  const float* W1s = (const float*)d_in[5];
  const float* W1d = (const float*)d_in[6];
  const float* W1e = (const float*)d_in[7];
  const float* b1s = (const float*)d_in[8];
  const float* b1d = (const float*)d_in[9];
  const float* att1 = (const float*)d_in[10];
  const float* bias1 = (const float*)d_in[11];
  const float* W2s = (const float*)d_in[12];
  const float* W2d = (const float*)d_in[13];
  const float* W2e = (const float*)d_in[14];
  const float* b2s = (const float*)d_in[15];
  const float* b2d = (const float*)d_in[16];
  const float* att2 = (const float*)d_in[17];
  const float* bias2 = (const float*)d_in[18];
  const float* W3s = (const float*)d_in[19];
  const float* W3d = (const float*)d_in[20];
  const float* W3e = (const float*)d_in[21];
  const float* b3s = (const float*)d_in[22];
  const float* b3d = (const float*)d_in[23];
  const float* att3 = (const float*)d_in[24];
  const float* bias3 = (const float*)d_in[25];
  const float* Wm1 = (const float*)d_in[26];
  const float* bm1 = (const float*)d_in[27];
  const float* Wm2 = (const float*)d_in[28];
  const float* bm2 = (const float*)d_in[29];

  // Workspace carve-up (~132 MB total).
  char* p = (char*)d_ws;
  auto take = [&](size_t bytes) {
    char* r = p;
    p += (bytes + 255) & ~(size_t)255;
    return r;
  };
  int* row_ptr = (int*)take((size_t)(kN + 1) * sizeof(int));
  int* counts = (int*)take((size_t)kN * sizeof(int));
  int* fill = (int*)take((size_t)kN * sizeof(int));
  int* csr_src = (int*)take((size_t)kE * sizeof(int));
  float* csr_ea = (float*)take((size_t)kE * 8 * sizeof(float));
  float* xs = (float*)take((size_t)kN * 128 * sizeof(float));
  float* xd = (float*)take((size_t)kN * 128 * sizeof(float));
  float* hA = (float*)take((size_t)kN * 128 * sizeof(float));
  float* hB = (float*)take((size_t)kN * 128 * sizeof(float));

  hipMemsetAsync(counts, 0, (size_t)kN * sizeof(int), stream);
  hipMemsetAsync(fill, 0, (size_t)kN * sizeof(int), stream);

  k_hist<<<(kE + 255) / 256, 256, 0, stream>>>(edst, counts, kE);
  k_scan<<<1, 1024, 0, stream>>>(counts, row_ptr, kN);
  k_scatter<<<(kE + 255) / 256, 256, 0, stream>>>(esrc, edst, eattr, row_ptr, fill,
                                                  csr_src, csr_ea, kE);

  // Layer 1: in=16 -> H=4, C=32 (D=128), ELU
  k_transform<16, 128><<<kN / 16, 128, 0, stream>>>(x, W1s, b1s, W1d, b1d, xs, xd, kN);
  k_gat<128, 4, true><<<kN / 4, 256, 0, stream>>>(row_ptr, csr_src, csr_ea, xs, xd,
                                                  att1, bias1, W1e, hA, kN);
  // Layer 2: in=128 -> D=128, ELU
  k_transform<128, 128><<<kN / 16, 128, 0, stream>>>(hA, W2s, b2s, W2d, b2d, xs, xd, kN);
  k_gat<128, 4, true><<<kN / 4, 256, 0, stream>>>(row_ptr, csr_src, csr_ea, xs, xd,
                                                  att2, bias2, W2e, hB, kN);
  // Layer 3: in=128 -> H=1, C=32 (D=32), no ELU
  k_transform<128, 32><<<kN / 16, 128, 0, stream>>>(hB, W3s, b3s, W3d, b3d, xs, xd, kN);
  k_gat<32, 1, false><<<kN / 4, 256, 0, stream>>>(row_ptr, csr_src, csr_ea, xs, xd,
                                                  att3, bias3, W3e, hA, kN);
  // Pool + MLP
  k_pool_mlp<<<kG, 64, 0, stream>>>(hA, batch, Wm1, bm1, Wm2, bm2, (float*)d_out, kN);
}

// Round 2
// 750.639 us; speedup vs baseline: 1.0734x; 1.0734x over previous
//
#include <hip/hip_runtime.h>
#include <cstdint>
#include <cstddef>

// Problem constants (fixed by the reference).
constexpr int kN = 50000;      // nodes
constexpr int kE = 800000;     // edges
constexpr int kG = 512;        // graphs
constexpr float kNegSlope = 0.2f;

// ---------------------------------------------------------------------------
// CSR build: histogram of dst -> block-scan (3 small kernels) -> scatter.
// ---------------------------------------------------------------------------
__global__ void k_hist(const int* __restrict__ dst, int* __restrict__ counts, int n) {
  int i = blockIdx.x * blockDim.x + threadIdx.x;
  if (i < n) atomicAdd(&counts[dst[i]], 1);
}

__global__ __launch_bounds__(256) void k_scan_blk(const int* __restrict__ counts,
                                                  int* __restrict__ excl,
                                                  int* __restrict__ bsums, int n) {
  __shared__ int sh[256];
  int tid = threadIdx.x;
  int i = blockIdx.x * 256 + tid;
  int c = (i < n) ? counts[i] : 0;
  sh[tid] = c;
  __syncthreads();
  for (int off = 1; off < 256; off <<= 1) {
    int t = (tid >= off) ? sh[tid - off] : 0;
    __syncthreads();
    sh[tid] += t;
    __syncthreads();
  }
  if (i < n) excl[i] = sh[tid] - c;
  if (tid == 255) bsums[blockIdx.x] = sh[255];
}

__global__ __launch_bounds__(256) void k_scan_top(const int* __restrict__ bsums,
                                                  int* __restrict__ boff,
                                                  int* __restrict__ row_ptr_last,
                                                  int nb) {
  __shared__ int sh[256];
  int tid = threadIdx.x;
  int c = (tid < nb) ? bsums[tid] : 0;
  sh[tid] = c;
  __syncthreads();
  for (int off = 1; off < 256; off <<= 1) {
    int t = (tid >= off) ? sh[tid - off] : 0;
    __syncthreads();
    sh[tid] += t;
    __syncthreads();
  }
  if (tid < nb) boff[tid] = sh[tid] - c;
  if (tid == 255) *row_ptr_last = sh[255];  // == total edge count
}

__global__ __launch_bounds__(256) void k_scan_add(const int* __restrict__ excl,
                                                  const int* __restrict__ boff,
                                                  int* __restrict__ row_ptr, int n) {
  int i = blockIdx.x * 256 + threadIdx.x;
  if (i < n) row_ptr[i] = excl[i] + boff[blockIdx.x];
}

__global__ void k_scatter(const int* __restrict__ src, const int* __restrict__ dst,
                          const float* __restrict__ eattr,
                          const int* __restrict__ row_ptr, int* __restrict__ fill,
                          int* __restrict__ csr_src, float* __restrict__ csr_ea, int n) {
  int i = blockIdx.x * blockDim.x + threadIdx.x;
  if (i >= n) return;
  int d = dst[i];
  int p = row_ptr[d] + atomicAdd(&fill[d], 1);
  csr_src[p] = src[i];
  const float4* s4 = (const float4*)eattr + (size_t)i * 2;
  float4* d4 = (float4*)csr_ea + (size_t)p * 2;
  d4[0] = s4[0];
  d4[1] = s4[1];
}

// ---------------------------------------------------------------------------
// Node transform: xs = h@Ws + bs ; xd = h@Wd + bd.
// ---------------------------------------------------------------------------
template <int IND, int OUTD>
__global__ __launch_bounds__(128) void k_transform(
    const float* __restrict__ h, const float* __restrict__ Ws, const float* __restrict__ bs,
    const float* __restrict__ Wd, const float* __restrict__ bd,
    float* __restrict__ xs, float* __restrict__ xd, int n_nodes) {
  constexpr int NPB = 16;            // nodes per block (50000 % 16 == 0)
  constexpr int GROUPS = 128 / OUTD; // 1 (OUTD=128) or 4 (OUTD=32)
  constexpr int NPT = NPB / GROUPS;  // nodes per thread
  __shared__ float sh[NPB][IND];
  int tid = threadIdx.x;
  int nb = blockIdx.x * NPB;
  for (int i = tid; i < NPB * IND; i += 128) {
    sh[i / IND][i % IND] = h[(size_t)(nb + i / IND) * IND + (i % IND)];
  }
  __syncthreads();
  int col = tid % OUTD;
  int g = tid / OUTD;
  float accs[NPT], accd[NPT];
  float bsv = bs[col], bdv = bd[col];
#pragma unroll
  for (int m = 0; m < NPT; ++m) { accs[m] = bsv; accd[m] = bdv; }
  for (int k = 0; k < IND; k += 2) {
    float ws0 = Ws[(size_t)k * OUTD + col], ws1 = Ws[(size_t)(k + 1) * OUTD + col];
    float wd0 = Wd[(size_t)k * OUTD + col], wd1 = Wd[(size_t)(k + 1) * OUTD + col];
#pragma unroll
    for (int m = 0; m < NPT; ++m) {
      float2 hv = *(const float2*)&sh[g * NPT + m][k];  // LDS broadcast, b64
      accs[m] += hv.x * ws0 + hv.y * ws1;
      accd[m] += hv.x * wd0 + hv.y * wd1;
    }
  }
#pragma unroll
  for (int m = 0; m < NPT; ++m) {
    int node = nb + g * NPT + m;
    if (node < n_nodes) {
      xs[(size_t)node * OUTD + col] = accs[m];
      xd[(size_t)node * OUTD + col] = accd[m];
    }
  }
}

// ---------------------------------------------------------------------------
// Fused GATv2 layer over CSR: one wave per destination node.
// Softmax WITHOUT running max (scores provably tiny: glorot x normal inputs
// => |score| < ~6 << 88 needed for expf overflow), so per-edge updates are
// commutative:  l += exp(sc);  acc += exp(sc)*xs.  This lets the wave process
// SLOTS edges concurrently (CPL=4 channels/lane => D=128:2 slots, D=32:8)
// and unroll-2 keeps 2*SLOTS independent gathers in flight.
// ---------------------------------------------------------------------------
template <int D, bool DO_ELU>
__global__ __launch_bounds__(256) void k_gat(
    const int* __restrict__ row_ptr, const int* __restrict__ csr_src,
    const float* __restrict__ csr_ea,
    const float* __restrict__ xs, const float* __restrict__ xd,
    const float* __restrict__ att, const float* __restrict__ bias,
    const float* __restrict__ We, float* __restrict__ hout, int n_nodes) {
  constexpr int SLOTS = 256 / D;   // edge slots per wave: 2 (D=128) / 8 (D=32)
  constexpr int LPS = D / 4;       // lanes per slot: 32 / 8
  constexpr int U = 2;             // unroll depth
  constexpr int EPI = SLOTS * U;   // edges per loop trip: 4 / 16
  int lane = threadIdx.x & 63;
  int node = blockIdx.x * (blockDim.x >> 6) + (threadIdx.x >> 6);
  if (node >= n_nodes) return;
  int slot = lane / LPS;
  int sl = lane % LPS;
  int ch0 = sl * 4;   // this lane's 4 channels (flat index; head = ch0/32)

  float4 xdv4 = *(const float4*)(xd + (size_t)node * D + ch0);
  float4 attv4 = *(const float4*)(att + ch0);
  float xdl[4] = {xdv4.x, xdv4.y, xdv4.z, xdv4.w};
  float attl[4] = {attv4.x, attv4.y, attv4.z, attv4.w};
  float wev[8][4];
#pragma unroll
  for (int k = 0; k < 8; ++k) {
    float4 w = *(const float4*)(We + k * D + ch0);
    wev[k][0] = w.x; wev[k][1] = w.y; wev[k][2] = w.z; wev[k][3] = w.w;
  }

  float acc[4] = {0.f, 0.f, 0.f, 0.f};
  float l_run = 0.f;

  int beg = row_ptr[node], end = row_ptr[node + 1];
  for (int base = beg; base < end; base += EPI) {
    int e[U]; bool v[U]; int s[U];
#pragma unroll
    for (int u = 0; u < U; ++u) {
      e[u] = base + u * SLOTS + slot;
      v[u] = e[u] < end;
      if (!v[u]) e[u] = beg;          // safe in-range edge; contribution masked
      s[u] = csr_src[e[u]];
    }
    float4 xsv[U], a0[U], a1[U];
#pragma unroll
    for (int u = 0; u < U; ++u) {
      xsv[u] = *(const float4*)(xs + (size_t)s[u] * D + ch0);
      const float4* ea4 = (const float4*)(csr_ea + (size_t)e[u] * 8);
      a0[u] = ea4[0];
      a1[u] = ea4[1];
    }
#pragma unroll
    for (int u = 0; u < U; ++u) {
      float ein[8] = {a0[u].x, a0[u].y, a0[u].z, a0[u].w,
                      a1[u].x, a1[u].y, a1[u].z, a1[u].w};
      float xsl[4] = {xsv[u].x, xsv[u].y, xsv[u].z, xsv[u].w};
      float sc = 0.f;
#pragma unroll
      for (int j = 0; j < 4; ++j) {
        float ea = 0.f;
#pragma unroll
        for (int k = 0; k < 8; ++k) ea += ein[k] * wev[k][j];
        float z = xsl[j] + xdl[j] + ea;
        z = fmaxf(z, kNegSlope * z);   // leaky_relu (slope<1)
        sc += z * attl[j];
      }
      // head-score reduction over the 8 lanes covering this head's 32 chans
      sc += __shfl_xor(sc, 1, 64);
      sc += __shfl_xor(sc, 2, 64);
      sc += __shfl_xor(sc, 4, 64);
      float p = v[u] ? __expf(sc) : 0.f;
      l_run += p;
#pragma unroll
      for (int j = 0; j < 4; ++j) acc[j] += p * xsl[j];
    }
  }

  // combine the SLOTS partial accumulations (lanes with equal sl)
#pragma unroll
  for (int off = LPS; off < 64; off <<= 1) {
    l_run += __shfl_xor(l_run, off, 64);
#pragma unroll
    for (int j = 0; j < 4; ++j) acc[j] += __shfl_xor(acc[j], off, 64);
  }

  if (slot == 0) {
    float inv = (l_run > 0.f) ? (1.f / l_run) : 0.f;  // isolated node -> bias
    float4 bv = *(const float4*)(bias + ch0);
    float bl[4] = {bv.x, bv.y, bv.z, bv.w};
    float4 ov;
    float o[4];
#pragma unroll
    for (int j = 0; j < 4; ++j) {
      float t = acc[j] * inv + bl[j];
      if (DO_ELU) t = (t > 0.f) ? t : (__expf(t) - 1.f);
      o[j] = t;
    }
    ov.x = o[0]; ov.y = o[1]; ov.z = o[2]; ov.w = o[3];
    *(float4*)(hout + (size_t)node * D + ch0) = ov;
  }
}

// ---------------------------------------------------------------------------
// Global mean-pool (batch is sorted -> binary-search ranges) + 2-layer MLP.
// ---------------------------------------------------------------------------
__device__ inline int lowerb(const int* a, int n, int v) {
  int lo = 0, hi = n;
  while (lo < hi) {
    int mid = (lo + hi) >> 1;
    if (a[mid] < v) lo = mid + 1; else hi = mid;
  }
  return lo;
}

__global__ __launch_bounds__(64) void k_pool_mlp(
    const float* __restrict__ h3, const int* __restrict__ batch,
    const float* __restrict__ Wm1, const float* __restrict__ bm1,
    const float* __restrict__ Wm2, const float* __restrict__ bm2,
    float* __restrict__ out, int n_nodes) {
  int g = blockIdx.x;
  int t = threadIdx.x;
  int lo = lowerb(batch, n_nodes, g);
  int hi = lowerb(batch, n_nodes, g + 1);
  int c = t & 31, half = t >> 5;
  float sum = 0.f;
  for (int i = lo + half; i < hi; i += 2) sum += h3[(size_t)i * 32 + c];
  sum += __shfl_xor(sum, 32, 64);
  float cnt = (float)(hi - lo);
  float emb = sum / fmaxf(cnt, 1.f);
  __shared__ float sh_emb[32];
  __shared__ float sh_hid[64];
  if (half == 0) sh_emb[c] = emb;
  __syncthreads();
  float hv = bm1[t];
  for (int k = 0; k < 32; ++k) hv += sh_emb[k] * Wm1[k * 64 + t];
  hv = fmaxf(hv, 0.f);
  sh_hid[t] = hv;
  __syncthreads();
  float ov = bm2[t];
  for (int k = 0; k < 64; ++k) ov += sh_hid[k] * Wm2[k * 64 + t];
  out[(size_t)g * 64 + t] = ov;
}

// ---------------------------------------------------------------------------
extern "C" void kernel_launch(void* const* d_in, const int* in_sizes, int n_in,
                              void* d_out, int out_size, void* d_ws, size_t ws_size,
                              hipStream_t stream) {
  const float* x = (const float*)d_in[0];
  const int* esrc = (const int*)d_in[1];
  const int* edst = (const int*)d_in[2];
  const float* eattr = (const float*)d_in[3];
  const int* batch = (const int*)d_in[4];
  const float* W1s = (const float*)d_in[5];
  const float* W1d = (const float*)d_in[6];
  const float* W1e = (const float*)d_in[7];
  const float* b1s = (const float*)d_in[8];
  const float* b1d = (const float*)d_in[9];
  const float* att1 = (const float*)d_in[10];
  const float* bias1 = (const float*)d_in[11];
  const float* W2s = (const float*)d_in[12];
  const float* W2d = (const float*)d_in[13];
  const float* W2e = (const float*)d_in[14];
  const float* b2s = (const float*)d_in[15];
  const float* b2d = (const float*)d_in[16];
  const float* att2 = (const float*)d_in[17];
  const float* bias2 = (const float*)d_in[18];
  const float* W3s = (const float*)d_in[19];
  const float* W3d = (const float*)d_in[20];
  const float* W3e = (const float*)d_in[21];
  const float* b3s = (const float*)d_in[22];
  const float* b3d = (const float*)d_in[23];
  const float* att3 = (const float*)d_in[24];
  const float* bias3 = (const float*)d_in[25];
  const float* Wm1 = (const float*)d_in[26];
  const float* bm1 = (const float*)d_in[27];
  const float* Wm2 = (const float*)d_in[28];
  const float* bm2 = (const float*)d_in[29];

  constexpr int kNB = (kN + 255) / 256;  // 196 scan blocks

  // Workspace carve-up (~132 MB total).
  char* p = (char*)d_ws;
  auto take = [&](size_t bytes) {
    char* r = p;
    p += (bytes + 255) & ~(size_t)255;
    return r;
  };
  int* row_ptr = (int*)take((size_t)(kN + 1) * sizeof(int));
  int* counts = (int*)take((size_t)kN * sizeof(int));
  int* fill = (int*)take((size_t)kN * sizeof(int));
  int* excl = (int*)take((size_t)kN * sizeof(int));
  int* bsums = (int*)take((size_t)kNB * sizeof(int));
  int* boff = (int*)take((size_t)kNB * sizeof(int));
  int* csr_src = (int*)take((size_t)kE * sizeof(int));
  float* csr_ea = (float*)take((size_t)kE * 8 * sizeof(float));
  float* xs = (float*)take((size_t)kN * 128 * sizeof(float));
  float* xd = (float*)take((size_t)kN * 128 * sizeof(float));
  float* hA = (float*)take((size_t)kN * 128 * sizeof(float));
  float* hB = (float*)take((size_t)kN * 128 * sizeof(float));

  hipMemsetAsync(counts, 0, (size_t)kN * sizeof(int), stream);
  hipMemsetAsync(fill, 0, (size_t)kN * sizeof(int), stream);

  k_hist<<<(kE + 255) / 256, 256, 0, stream>>>(edst, counts, kE);
  k_scan_blk<<<kNB, 256, 0, stream>>>(counts, excl, bsums, kN);
  k_scan_top<<<1, 256, 0, stream>>>(bsums, boff, row_ptr + kN, kNB);
  k_scan_add<<<kNB, 256, 0, stream>>>(excl, boff, row_ptr, kN);
  k_scatter<<<(kE + 255) / 256, 256, 0, stream>>>(esrc, edst, eattr, row_ptr, fill,
                                                  csr_src, csr_ea, kE);

  // Layer 1: in=16 -> H=4, C=32 (D=128), ELU
  k_transform<16, 128><<<kN / 16, 128, 0, stream>>>(x, W1s, b1s, W1d, b1d, xs, xd, kN);
  k_gat<128, true><<<kN / 4, 256, 0, stream>>>(row_ptr, csr_src, csr_ea, xs, xd,
                                               att1, bias1, W1e, hA, kN);
  // Layer 2: in=128 -> D=128, ELU
  k_transform<128, 128><<<kN / 16, 128, 0, stream>>>(hA, W2s, b2s, W2d, b2d, xs, xd, kN);
  k_gat<128, true><<<kN / 4, 256, 0, stream>>>(row_ptr, csr_src, csr_ea, xs, xd,
                                               att2, bias2, W2e, hB, kN);
  // Layer 3: in=128 -> H=1, C=32 (D=32), no ELU
  k_transform<128, 32><<<kN / 16, 128, 0, stream>>>(hB, W3s, b3s, W3d, b3d, xs, xd, kN);
  k_gat<32, false><<<kN / 4, 256, 0, stream>>>(row_ptr, csr_src, csr_ea, xs, xd,
                                               att3, bias3, W3e, hA, kN);
  // Pool + MLP
  k_pool_mlp<<<kG, 64, 0, stream>>>(hA, batch, Wm1, bm1, Wm2, bm2, (float*)d_out, kN);
}

// Round 3
// 605.905 us; speedup vs baseline: 1.3298x; 1.2389x over previous
//
#include <hip/hip_runtime.h>
#include <cstdint>
#include <cstddef>

// Problem constants (fixed by the reference).
constexpr int kN = 50000;      // nodes
constexpr int kE = 800000;     // edges
constexpr int kG = 512;        // graphs
constexpr float kNegSlope = 0.2f;

typedef float f4v __attribute__((ext_vector_type(4)));
typedef float f2v __attribute__((ext_vector_type(2)));

__device__ inline f4v nt_load4(const float* p) {
  return __builtin_nontemporal_load((const f4v*)p);
}

// ---------------------------------------------------------------------------
// CSR build: histogram of dst -> block-scan (3 small kernels) -> scatter.
// ---------------------------------------------------------------------------
__global__ void k_hist(const int* __restrict__ dst, int* __restrict__ counts, int n) {
  int i = blockIdx.x * blockDim.x + threadIdx.x;
  if (i < n) atomicAdd(&counts[dst[i]], 1);
}

__global__ __launch_bounds__(256) void k_scan_blk(const int* __restrict__ counts,
                                                  int* __restrict__ excl,
                                                  int* __restrict__ bsums, int n) {
  __shared__ int sh[256];
  int tid = threadIdx.x;
  int i = blockIdx.x * 256 + tid;
  int c = (i < n) ? counts[i] : 0;
  sh[tid] = c;
  __syncthreads();
  for (int off = 1; off < 256; off <<= 1) {
    int t = (tid >= off) ? sh[tid - off] : 0;
    __syncthreads();
    sh[tid] += t;
    __syncthreads();
  }
  if (i < n) excl[i] = sh[tid] - c;
  if (tid == 255) bsums[blockIdx.x] = sh[255];
}

__global__ __launch_bounds__(256) void k_scan_top(const int* __restrict__ bsums,
                                                  int* __restrict__ boff,
                                                  int* __restrict__ row_ptr_last,
                                                  int nb) {
  __shared__ int sh[256];
  int tid = threadIdx.x;
  int c = (tid < nb) ? bsums[tid] : 0;
  sh[tid] = c;
  __syncthreads();
  for (int off = 1; off < 256; off <<= 1) {
    int t = (tid >= off) ? sh[tid - off] : 0;
    __syncthreads();
    sh[tid] += t;
    __syncthreads();
  }
  if (tid < nb) boff[tid] = sh[tid] - c;
  if (tid == 255) *row_ptr_last = sh[255];
}

__global__ __launch_bounds__(256) void k_scan_add(const int* __restrict__ excl,
                                                  const int* __restrict__ boff,
                                                  int* __restrict__ row_ptr, int n) {
  int i = blockIdx.x * 256 + threadIdx.x;
  if (i < n) row_ptr[i] = excl[i] + boff[blockIdx.x];
}

__global__ void k_scatter(const int* __restrict__ src, const int* __restrict__ dst,
                          const float* __restrict__ eattr,
                          const int* __restrict__ row_ptr, int* __restrict__ fill,
                          int* __restrict__ csr_src, float* __restrict__ csr_ea, int n) {
  int i = blockIdx.x * blockDim.x + threadIdx.x;
  if (i >= n) return;
  int d = dst[i];
  int p = row_ptr[d] + atomicAdd(&fill[d], 1);
  csr_src[p] = src[i];
  const float4* s4 = (const float4*)eattr + (size_t)i * 2;
  float4* d4 = (float4*)csr_ea + (size_t)p * 2;
  d4[0] = s4[0];
  d4[1] = s4[1];
}

// ---------------------------------------------------------------------------
// Node transform: xs = h@Ws + bs ; xd = h@Wd + bd.
// ---------------------------------------------------------------------------
template <int IND, int OUTD>
__global__ __launch_bounds__(128) void k_transform(
    const float* __restrict__ h, const float* __restrict__ Ws, const float* __restrict__ bs,
    const float* __restrict__ Wd, const float* __restrict__ bd,
    float* __restrict__ xs, float* __restrict__ xd, int n_nodes) {
  constexpr int NPB = 16;
  constexpr int GROUPS = 128 / OUTD;
  constexpr int NPT = NPB / GROUPS;
  __shared__ float sh[NPB][IND];
  int tid = threadIdx.x;
  int nb = blockIdx.x * NPB;
  for (int i = tid; i < NPB * IND; i += 128) {
    sh[i / IND][i % IND] = h[(size_t)(nb + i / IND) * IND + (i % IND)];
  }
  __syncthreads();
  int col = tid % OUTD;
  int g = tid / OUTD;
  float accs[NPT], accd[NPT];
  float bsv = bs[col], bdv = bd[col];
#pragma unroll
  for (int m = 0; m < NPT; ++m) { accs[m] = bsv; accd[m] = bdv; }
  for (int k = 0; k < IND; k += 2) {
    float ws0 = Ws[(size_t)k * OUTD + col], ws1 = Ws[(size_t)(k + 1) * OUTD + col];
    float wd0 = Wd[(size_t)k * OUTD + col], wd1 = Wd[(size_t)(k + 1) * OUTD + col];
#pragma unroll
    for (int m = 0; m < NPT; ++m) {
      float2 hv = *(const float2*)&sh[g * NPT + m][k];
      accs[m] += hv.x * ws0 + hv.y * ws1;
      accd[m] += hv.x * wd0 + hv.y * wd1;
    }
  }
#pragma unroll
  for (int m = 0; m < NPT; ++m) {
    int node = nb + g * NPT + m;
    if (node < n_nodes) {
      xs[(size_t)node * OUTD + col] = accs[m];
      xd[(size_t)node * OUTD + col] = accd[m];
    }
  }
}

// ---------------------------------------------------------------------------
// Fused GATv2, D=128 (H=4, C=32): one wave per dst node, whole wave per edge
// (lane holds channels 2*lane, 2*lane+1).  No-max softmax (scores bounded
// ~|6| << 88).  Per 64-edge chunk: src ids preloaded per-lane + readlane
// broadcast; edge attrs staged via LDS (2 coalesced dwordx4 per chunk);
// xs gathers software-pipelined at distance 2.
// ---------------------------------------------------------------------------
template <bool DO_ELU>
__global__ __launch_bounds__(256) void k_gat128(
    const int* __restrict__ row_ptr, const int* __restrict__ csr_src,
    const float* __restrict__ csr_ea,
    const float* __restrict__ xs, const float* __restrict__ xd,
    const float* __restrict__ att, const float* __restrict__ bias,
    const float* __restrict__ We, float* __restrict__ hout, int n_nodes) {
  __shared__ float sea[4][64 * 8];
  int lane = threadIdx.x & 63;
  int wid = threadIdx.x >> 6;
  int node = blockIdx.x * 4 + wid;
  if (node >= n_nodes) return;
  int ch0 = lane * 2;

  float2 xdv = *(const float2*)(xd + (size_t)node * 128 + ch0);
  float2 attv = *(const float2*)(att + ch0);
  float wev[8][2];
#pragma unroll
  for (int k = 0; k < 8; ++k) {
    float2 w = *(const float2*)(We + k * 128 + ch0);
    wev[k][0] = w.x;
    wev[k][1] = w.y;
  }

  float acc0 = 0.f, acc1 = 0.f, l_run = 0.f;
  int beg = row_ptr[node], end = row_ptr[node + 1];

  for (int cbeg = beg; cbeg < end; cbeg += 64) {
    int cnt = min(end - cbeg, 64);
    int sv = (lane < cnt) ? __builtin_nontemporal_load(csr_src + cbeg + lane) : 0;
    // stage this chunk's edge attrs into wave-private LDS (coalesced)
    if (lane < cnt) {
      const float* pe = csr_ea + (size_t)(cbeg + lane) * 8;
      f4v t0 = nt_load4(pe);
      f4v t1 = nt_load4(pe + 4);
      *(f4v*)&sea[wid][lane * 8] = t0;
      *(f4v*)&sea[wid][lane * 8 + 4] = t1;
    }

    auto gat_load = [&](int i) -> float2 {
      int idx = min(i, cnt - 1);
      idx = max(idx, 0);
      int s = __shfl(sv, idx, 64);
      return *(const float2*)(xs + (size_t)s * 128 + ch0);
    };
    auto compute = [&](int i, float2 c) {
      float4 a0 = *(const float4*)&sea[wid][i * 8];
      float4 a1 = *(const float4*)&sea[wid][i * 8 + 4];
      float e0 = a0.x * wev[0][0] + a0.y * wev[1][0] + a0.z * wev[2][0] + a0.w * wev[3][0] +
                 a1.x * wev[4][0] + a1.y * wev[5][0] + a1.z * wev[6][0] + a1.w * wev[7][0];
      float e1 = a0.x * wev[0][1] + a0.y * wev[1][1] + a0.z * wev[2][1] + a0.w * wev[3][1] +
                 a1.x * wev[4][1] + a1.y * wev[5][1] + a1.z * wev[6][1] + a1.w * wev[7][1];
      float z0 = c.x + xdv.x + e0;
      float z1 = c.y + xdv.y + e1;
      z0 = fmaxf(z0, kNegSlope * z0);
      z1 = fmaxf(z1, kNegSlope * z1);
      float sc = z0 * attv.x + z1 * attv.y;
      sc += __shfl_xor(sc, 1, 64);
      sc += __shfl_xor(sc, 2, 64);
      sc += __shfl_xor(sc, 4, 64);
      sc += __shfl_xor(sc, 8, 64);   // head = 16 lanes (32 ch, 2/lane)
      float p = __expf(sc);
      l_run += p;
      acc0 += p * c.x;
      acc1 += p * c.y;
    };

    float2 x0 = gat_load(0);
    float2 x1 = gat_load(1);
    int i = 0;
    for (; i + 2 <= cnt; i += 2) {
      float2 c0 = x0, c1 = x1;
      x0 = gat_load(i + 2);
      x1 = gat_load(i + 3);
      compute(i, c0);
      compute(i + 1, c1);
    }
    if (i < cnt) compute(i, x0);
  }

  float inv = (l_run > 0.f) ? (1.f / l_run) : 0.f;
  float2 bv = *(const float2*)(bias + ch0);
  float o0 = acc0 * inv + bv.x;
  float o1 = acc1 * inv + bv.y;
  if (DO_ELU) {
    o0 = (o0 > 0.f) ? o0 : (__expf(o0) - 1.f);
    o1 = (o1 > 0.f) ? o1 : (__expf(o1) - 1.f);
  }
  f2v ov;
  ov.x = o0;
  ov.y = o1;
  __builtin_nontemporal_store(ov, (f2v*)(hout + (size_t)node * 128 + ch0));
}

// ---------------------------------------------------------------------------
// Fused GATv2, D=32 (H=1, C=32): TWO nodes per wave (half-wave each, 1 ch per
// lane).  Same chunked structure, 32 edges per half-chunk.
// ---------------------------------------------------------------------------
template <bool DO_ELU>
__global__ __launch_bounds__(256) void k_gat32(
    const int* __restrict__ row_ptr, const int* __restrict__ csr_src,
    const float* __restrict__ csr_ea,
    const float* __restrict__ xs, const float* __restrict__ xd,
    const float* __restrict__ att, const float* __restrict__ bias,
    const float* __restrict__ We, float* __restrict__ hout, int n_nodes) {
  __shared__ float sea[4][2 * 32 * 8];
  int lane = threadIdx.x & 63;
  int wid = threadIdx.x >> 6;
  int half = lane >> 5;
  int hl = lane & 31;
  int node = blockIdx.x * 8 + wid * 2 + half;
  if (node >= n_nodes) return;
  int ch = hl;

  float xdv = xd[(size_t)node * 32 + ch];
  float attv = att[ch];
  float wev[8];
#pragma unroll
  for (int k = 0; k < 8; ++k) wev[k] = We[k * 32 + ch];

  float acc = 0.f, l_run = 0.f;
  int beg = row_ptr[node], end = row_ptr[node + 1];
  int deg = end - beg;
  int um = max(deg, __shfl_xor(deg, 32, 64));  // uniform max degree over wave

  for (int cb = 0; cb < um; cb += 32) {
    int cbeg = beg + cb;
    int cnt = min(end - cbeg, 32);  // may be <= 0 for this half
    int sv = (hl < cnt) ? __builtin_nontemporal_load(csr_src + cbeg + hl) : 0;
    if (hl < cnt) {
      const float* pe = csr_ea + (size_t)(cbeg + hl) * 8;
      f4v t0 = nt_load4(pe);
      f4v t1 = nt_load4(pe + 4);
      *(f4v*)&sea[wid][half * 256 + hl * 8] = t0;
      *(f4v*)&sea[wid][half * 256 + hl * 8 + 4] = t1;
    }

    auto gat_load = [&](int i) -> float {
      int idx = min(i, cnt - 1);
      idx = max(idx, 0);
      int s = __shfl(sv, half * 32 + idx, 64);
      return xs[(size_t)s * 32 + ch];
    };
    auto compute = [&](int i, float c) {
      float4 a0 = *(const float4*)&sea[wid][half * 256 + i * 8];
      float4 a1 = *(const float4*)&sea[wid][half * 256 + i * 8 + 4];
      float e = a0.x * wev[0] + a0.y * wev[1] + a0.z * wev[2] + a0.w * wev[3] +
                a1.x * wev[4] + a1.y * wev[5] + a1.z * wev[6] + a1.w * wev[7];
      float z = c + xdv + e;
      z = fmaxf(z, kNegSlope * z);
      float sc = z * attv;
      sc += __shfl_xor(sc, 1, 64);
      sc += __shfl_xor(sc, 2, 64);
      sc += __shfl_xor(sc, 4, 64);
      sc += __shfl_xor(sc, 8, 64);
      sc += __shfl_xor(sc, 16, 64);  // head = 32 lanes within the half
      float p = (i < cnt) ? __expf(sc) : 0.f;
      l_run += p;
      acc += p * c;
    };

    int icnt = min(um - cb, 32);  // uniform inner bound
    float x0 = gat_load(0);
    float x1 = gat_load(1);
    int i = 0;
    for (; i + 2 <= icnt; i += 2) {
      float c0 = x0, c1 = x1;
      x0 = gat_load(i + 2);
      x1 = gat_load(i + 3);
      compute(i, c0);
      compute(i + 1, c1);
    }
    if (i < icnt) compute(i, x0);
  }

  float inv = (l_run > 0.f) ? (1.f / l_run) : 0.f;
  float o = acc * inv + bias[ch];
  if (DO_ELU) o = (o > 0.f) ? o : (__expf(o) - 1.f);
  __builtin_nontemporal_store(o, hout + (size_t)node * 32 + ch);
}

// ---------------------------------------------------------------------------
// Global mean-pool + 2-layer MLP.
// ---------------------------------------------------------------------------
__device__ inline int lowerb(const int* a, int n, int v) {
  int lo = 0, hi = n;
  while (lo < hi) {
    int mid = (lo + hi) >> 1;
    if (a[mid] < v) lo = mid + 1; else hi = mid;
  }
  return lo;
}

__global__ __launch_bounds__(64) void k_pool_mlp(
    const float* __restrict__ h3, const int* __restrict__ batch,
    const float* __restrict__ Wm1, const float* __restrict__ bm1,
    const float* __restrict__ Wm2, const float* __restrict__ bm2,
    float* __restrict__ out, int n_nodes) {
  int g = blockIdx.x;
  int t = threadIdx.x;
  int lo = lowerb(batch, n_nodes, g);
  int hi = lowerb(batch, n_nodes, g + 1);
  int c = t & 31, half = t >> 5;
  float sum = 0.f;
  for (int i = lo + half; i < hi; i += 2) sum += h3[(size_t)i * 32 + c];
  sum += __shfl_xor(sum, 32, 64);
  float cnt = (float)(hi - lo);
  float emb = sum / fmaxf(cnt, 1.f);
  __shared__ float sh_emb[32];
  __shared__ float sh_hid[64];
  if (half == 0) sh_emb[c] = emb;
  __syncthreads();
  float hv = bm1[t];
  for (int k = 0; k < 32; ++k) hv += sh_emb[k] * Wm1[k * 64 + t];
  hv = fmaxf(hv, 0.f);
  sh_hid[t] = hv;
  __syncthreads();
  float ov = bm2[t];
  for (int k = 0; k < 64; ++k) ov += sh_hid[k] * Wm2[k * 64 + t];
  out[(size_t)g * 64 + t] = ov;
}

// ---------------------------------------------------------------------------
extern "C" void kernel_launch(void* const* d_in, const int* in_sizes, int n_in,
                              void* d_out, int out_size, void* d_ws, size_t ws_size,
                              hipStream_t stream) {
  const float* x = (const float*)d_in[0];
  const int* esrc = (const int*)d_in[1];
  const int* edst = (const int*)d_in[2];
  const float* eattr = (const float*)d_in[3];
  const int* batch = (const int*)d_in[4];
  const float* W1s = (const float*)d_in[5];
  const float* W1d = (const float*)d_in[6];
  const float* W1e = (const float*)d_in[7];
  const float* b1s = (const float*)d_in[8];
  const float* b1d = (const float*)d_in[9];
  const float* att1 = (const float*)d_in[10];
  const float* bias1 = (const float*)d_in[11];
  const float* W2s = (const float*)d_in[12];
  const float* W2d = (const float*)d_in[13];
  const float* W2e = (const float*)d_in[14];
  const float* b2s = (const float*)d_in[15];
  const float* b2d = (const float*)d_in[16];
  const float* att2 = (const float*)d_in[17];
  const float* bias2 = (const float*)d_in[18];
  const float* W3s = (const float*)d_in[19];
  const float* W3d = (const float*)d_in[20];
  const float* W3e = (const float*)d_in[21];
  const float* b3s = (const float*)d_in[22];
  const float* b3d = (const float*)d_in[23];
  const float* att3 = (const float*)d_in[24];
  const float* bias3 = (const float*)d_in[25];
  const float* Wm1 = (const float*)d_in[26];
  const float* bm1 = (const float*)d_in[27];
  const float* Wm2 = (const float*)d_in[28];
  const float* bm2 = (const float*)d_in[29];

  constexpr int kNB = (kN + 255) / 256;

  char* p = (char*)d_ws;
  auto take = [&](size_t bytes) {
    char* r = p;
    p += (bytes + 255) & ~(size_t)255;
    return r;
  };
  int* row_ptr = (int*)take((size_t)(kN + 1) * sizeof(int));
  int* counts = (int*)take((size_t)kN * sizeof(int));
  int* fill = (int*)take((size_t)kN * sizeof(int));
  int* excl = (int*)take((size_t)kN * sizeof(int));
  int* bsums = (int*)take((size_t)kNB * sizeof(int));
  int* boff = (int*)take((size_t)kNB * sizeof(int));
  int* csr_src = (int*)take((size_t)kE * sizeof(int));
  float* csr_ea = (float*)take((size_t)kE * 8 * sizeof(float));
  float* xs = (float*)take((size_t)kN * 128 * sizeof(float));
  float* xd = (float*)take((size_t)kN * 128 * sizeof(float));
  float* hA = (float*)take((size_t)kN * 128 * sizeof(float));
  float* hB = (float*)take((size_t)kN * 128 * sizeof(float));

  hipMemsetAsync(counts, 0, (size_t)kN * sizeof(int), stream);
  hipMemsetAsync(fill, 0, (size_t)kN * sizeof(int), stream);

  k_hist<<<(kE + 255) / 256, 256, 0, stream>>>(edst, counts, kE);
  k_scan_blk<<<kNB, 256, 0, stream>>>(counts, excl, bsums, kN);
  k_scan_top<<<1, 256, 0, stream>>>(bsums, boff, row_ptr + kN, kNB);
  k_scan_add<<<kNB, 256, 0, stream>>>(excl, boff, row_ptr, kN);
  k_scatter<<<(kE + 255) / 256, 256, 0, stream>>>(esrc, edst, eattr, row_ptr, fill,
                                                  csr_src, csr_ea, kE);

  // Layer 1: in=16 -> H=4, C=32 (D=128), ELU
  k_transform<16, 128><<<kN / 16, 128, 0, stream>>>(x, W1s, b1s, W1d, b1d, xs, xd, kN);
  k_gat128<true><<<kN / 4, 256, 0, stream>>>(row_ptr, csr_src, csr_ea, xs, xd,
                                             att1, bias1, W1e, hA, kN);
  // Layer 2: in=128 -> D=128, ELU
  k_transform<128, 128><<<kN / 16, 128, 0, stream>>>(hA, W2s, b2s, W2d, b2d, xs, xd, kN);
  k_gat128<true><<<kN / 4, 256, 0, stream>>>(row_ptr, csr_src, csr_ea, xs, xd,
                                             att2, bias2, W2e, hB, kN);
  // Layer 3: in=128 -> H=1, C=32 (D=32), no ELU
  k_transform<128, 32><<<kN / 16, 128, 0, stream>>>(hB, W3s, b3s, W3d, b3d, xs, xd, kN);
  k_gat32<false><<<kN / 8, 256, 0, stream>>>(row_ptr, csr_src, csr_ea, xs, xd,
                                             att3, bias3, W3e, hA, kN);
  // Pool + MLP
  k_pool_mlp<<<kG, 64, 0, stream>>>(hA, batch, Wm1, bm1, Wm2, bm2, (float*)d_out, kN);
}

// Round 4
// 561.488 us; speedup vs baseline: 1.4350x; 1.0791x over previous
//
#include <hip/hip_runtime.h>
#include <cstdint>
#include <cstddef>

// Problem constants (fixed by the reference).
constexpr int kN = 50000;      // nodes  (< 65536 -> src ids fit in uint16)
constexpr int kE = 800000;     // edges
constexpr int kG = 512;        // graphs
constexpr float kNegSlope = 0.2f;

typedef float f4v __attribute__((ext_vector_type(4)));
typedef float f2v __attribute__((ext_vector_type(2)));
typedef _Float16 h2v __attribute__((ext_vector_type(2)));
typedef _Float16 h8v __attribute__((ext_vector_type(8)));

#if defined(__has_builtin)
#if __has_builtin(__builtin_amdgcn_fdot2)
#define HAS_FDOT2 1
#endif
#endif

__device__ inline float dot2f(h2v a, h2v b, float c) {
#ifdef HAS_FDOT2
  return __builtin_amdgcn_fdot2(a, b, c, false);
#else
  return c + (float)a.x * (float)b.x + (float)a.y * (float)b.y;
#endif
}

// ---------------------------------------------------------------------------
// CSR build: histogram of dst -> block-scan -> scatter (fp16 edge attrs,
// u16 src ids).
// ---------------------------------------------------------------------------
__global__ void k_hist(const int* __restrict__ dst, int* __restrict__ counts, int n) {
  int i = blockIdx.x * blockDim.x + threadIdx.x;
  if (i < n) atomicAdd(&counts[dst[i]], 1);
}

__global__ __launch_bounds__(256) void k_scan_blk(const int* __restrict__ counts,
                                                  int* __restrict__ excl,
                                                  int* __restrict__ bsums, int n) {
  __shared__ int sh[256];
  int tid = threadIdx.x;
  int i = blockIdx.x * 256 + tid;
  int c = (i < n) ? counts[i] : 0;
  sh[tid] = c;
  __syncthreads();
  for (int off = 1; off < 256; off <<= 1) {
    int t = (tid >= off) ? sh[tid - off] : 0;
    __syncthreads();
    sh[tid] += t;
    __syncthreads();
  }
  if (i < n) excl[i] = sh[tid] - c;
  if (tid == 255) bsums[blockIdx.x] = sh[255];
}

__global__ __launch_bounds__(256) void k_scan_top(const int* __restrict__ bsums,
                                                  int* __restrict__ boff,
                                                  int* __restrict__ row_ptr_last,
                                                  int nb) {
  __shared__ int sh[256];
  int tid = threadIdx.x;
  int c = (tid < nb) ? bsums[tid] : 0;
  sh[tid] = c;
  __syncthreads();
  for (int off = 1; off < 256; off <<= 1) {
    int t = (tid >= off) ? sh[tid - off] : 0;
    __syncthreads();
    sh[tid] += t;
    __syncthreads();
  }
  if (tid < nb) boff[tid] = sh[tid] - c;
  if (tid == 255) *row_ptr_last = sh[255];
}

__global__ __launch_bounds__(256) void k_scan_add(const int* __restrict__ excl,
                                                  const int* __restrict__ boff,
                                                  int* __restrict__ row_ptr, int n) {
  int i = blockIdx.x * 256 + threadIdx.x;
  if (i < n) row_ptr[i] = excl[i] + boff[blockIdx.x];
}

__global__ void k_scatter(const int* __restrict__ src, const int* __restrict__ dst,
                          const float* __restrict__ eattr,
                          const int* __restrict__ row_ptr, int* __restrict__ fill,
                          uint16_t* __restrict__ csr_src, _Float16* __restrict__ csr_ea,
                          int n) {
  int i = blockIdx.x * blockDim.x + threadIdx.x;
  if (i >= n) return;
  int d = dst[i];
  int p = row_ptr[d] + atomicAdd(&fill[d], 1);
  csr_src[p] = (uint16_t)src[i];
  const float4* s4 = (const float4*)eattr + (size_t)i * 2;
  float4 a = s4[0];
  float4 b = s4[1];
  h8v hv;
  hv[0] = (_Float16)a.x; hv[1] = (_Float16)a.y; hv[2] = (_Float16)a.z; hv[3] = (_Float16)a.w;
  hv[4] = (_Float16)b.x; hv[5] = (_Float16)b.y; hv[6] = (_Float16)b.z; hv[7] = (_Float16)b.w;
  *(h8v*)(csr_ea + (size_t)p * 8) = hv;
}

// ---------------------------------------------------------------------------
// Node transform: xs = h@Ws + bs (stored fp16) ; xd = h@Wd + bd (fp32).
// ---------------------------------------------------------------------------
template <int IND, int OUTD>
__global__ __launch_bounds__(128) void k_transform(
    const float* __restrict__ h, const float* __restrict__ Ws, const float* __restrict__ bs,
    const float* __restrict__ Wd, const float* __restrict__ bd,
    _Float16* __restrict__ xs_h, float* __restrict__ xd, int n_nodes) {
  constexpr int NPB = 16;
  constexpr int GROUPS = 128 / OUTD;
  constexpr int NPT = NPB / GROUPS;
  __shared__ float sh[NPB][IND];
  int tid = threadIdx.x;
  int nb = blockIdx.x * NPB;
  for (int i = tid; i < NPB * IND; i += 128) {
    sh[i / IND][i % IND] = h[(size_t)(nb + i / IND) * IND + (i % IND)];
  }
  __syncthreads();
  int col = tid % OUTD;
  int g = tid / OUTD;
  float accs[NPT], accd[NPT];
  float bsv = bs[col], bdv = bd[col];
#pragma unroll
  for (int m = 0; m < NPT; ++m) { accs[m] = bsv; accd[m] = bdv; }
  for (int k = 0; k < IND; k += 2) {
    float ws0 = Ws[(size_t)k * OUTD + col], ws1 = Ws[(size_t)(k + 1) * OUTD + col];
    float wd0 = Wd[(size_t)k * OUTD + col], wd1 = Wd[(size_t)(k + 1) * OUTD + col];
#pragma unroll
    for (int m = 0; m < NPT; ++m) {
      float2 hv = *(const float2*)&sh[g * NPT + m][k];
      accs[m] += hv.x * ws0 + hv.y * ws1;
      accd[m] += hv.x * wd0 + hv.y * wd1;
    }
  }
#pragma unroll
  for (int m = 0; m < NPT; ++m) {
    int node = nb + g * NPT + m;
    if (node < n_nodes) {
      xs_h[(size_t)node * OUTD + col] = (_Float16)accs[m];
      xd[(size_t)node * OUTD + col] = accd[m];
    }
  }
}

// ---------------------------------------------------------------------------
// Fused GATv2, D=128 (H=4, C=32): one wave per dst node, whole wave per edge
// (lane holds channels 2*lane, 2*lane+1).  No-max softmax (scores bounded
// ~|6| << 88).  fp16 gathers (256 B/row), fp16 edge attrs staged via LDS,
// v_dot2_f32_f16 score math, fp32 accumulation.
// ---------------------------------------------------------------------------
template <bool DO_ELU>
__global__ __launch_bounds__(256) void k_gat128(
    const int* __restrict__ row_ptr, const uint16_t* __restrict__ csr_src,
    const _Float16* __restrict__ csr_ea,
    const _Float16* __restrict__ xs_h, const float* __restrict__ xd,
    const float* __restrict__ att, const float* __restrict__ bias,
    const float* __restrict__ We, float* __restrict__ hout, int n_nodes) {
  __shared__ _Float16 sea[4][64 * 8];
  int lane = threadIdx.x & 63;
  int wid = threadIdx.x >> 6;
  int node = blockIdx.x * 4 + wid;
  if (node >= n_nodes) return;
  int ch0 = lane * 2;

  float2 xdv = *(const float2*)(xd + (size_t)node * 128 + ch0);
  float2 attv = *(const float2*)(att + ch0);
  // We columns (ch0, ch0+1) as fp16 pairs over the 8 edge dims.
  h2v wh0[4], wh1[4];
#pragma unroll
  for (int t = 0; t < 4; ++t) {
    float2 wa = *(const float2*)(We + (2 * t) * 128 + ch0);
    float2 wb = *(const float2*)(We + (2 * t + 1) * 128 + ch0);
    wh0[t][0] = (_Float16)wa.x; wh0[t][1] = (_Float16)wb.x;
    wh1[t][0] = (_Float16)wa.y; wh1[t][1] = (_Float16)wb.y;
  }

  float acc0 = 0.f, acc1 = 0.f, l_run = 0.f;
  int beg = row_ptr[node], end = row_ptr[node + 1];

  for (int cbeg = beg; cbeg < end; cbeg += 64) {
    int cnt = min(end - cbeg, 64);
    int sv = (lane < cnt) ? (int)__builtin_nontemporal_load(csr_src + cbeg + lane) : 0;
    if (lane < cnt) {
      h8v t = __builtin_nontemporal_load((const h8v*)(csr_ea + (size_t)(cbeg + lane) * 8));
      *(h8v*)&sea[wid][lane * 8] = t;
    }

    auto gat_load = [&](int i) -> h2v {
      int idx = min(i, cnt - 1);
      idx = max(idx, 0);
      int s = __shfl(sv, idx, 64);
      return *(const h2v*)(xs_h + (size_t)s * 128 + ch0);
    };
    auto compute = [&](int i, h2v xh) {
      const _Float16* pe = &sea[wid][i * 8];
      h2v a0 = *(const h2v*)(pe);
      h2v a1 = *(const h2v*)(pe + 2);
      h2v a2 = *(const h2v*)(pe + 4);
      h2v a3 = *(const h2v*)(pe + 6);
      float e0 = dot2f(a3, wh0[3], dot2f(a2, wh0[2], dot2f(a1, wh0[1], dot2f(a0, wh0[0], 0.f))));
      float e1 = dot2f(a3, wh1[3], dot2f(a2, wh1[2], dot2f(a1, wh1[1], dot2f(a0, wh1[0], 0.f))));
      float cx = (float)xh.x, cy = (float)xh.y;
      float z0 = cx + xdv.x + e0;
      float z1 = cy + xdv.y + e1;
      z0 = fmaxf(z0, kNegSlope * z0);
      z1 = fmaxf(z1, kNegSlope * z1);
      float sc = z0 * attv.x + z1 * attv.y;
      sc += __shfl_xor(sc, 1, 64);
      sc += __shfl_xor(sc, 2, 64);
      sc += __shfl_xor(sc, 4, 64);
      sc += __shfl_xor(sc, 8, 64);   // head = 16 lanes (32 ch, 2/lane)
      float p = __expf(sc);
      l_run += p;
      acc0 += p * cx;
      acc1 += p * cy;
    };

    h2v x0 = gat_load(0);
    h2v x1 = gat_load(1);
    int i = 0;
    for (; i + 2 <= cnt; i += 2) {
      h2v c0 = x0, c1 = x1;
      x0 = gat_load(i + 2);
      x1 = gat_load(i + 3);
      compute(i, c0);
      compute(i + 1, c1);
    }
    if (i < cnt) compute(i, x0);
  }

  float inv = (l_run > 0.f) ? (1.f / l_run) : 0.f;
  float2 bv = *(const float2*)(bias + ch0);
  float o0 = acc0 * inv + bv.x;
  float o1 = acc1 * inv + bv.y;
  if (DO_ELU) {
    o0 = (o0 > 0.f) ? o0 : (__expf(o0) - 1.f);
    o1 = (o1 > 0.f) ? o1 : (__expf(o1) - 1.f);
  }
  f2v ov;
  ov.x = o0;
  ov.y = o1;
  __builtin_nontemporal_store(ov, (f2v*)(hout + (size_t)node * 128 + ch0));
}

// ---------------------------------------------------------------------------
// Fused GATv2, D=32 (H=1, C=32): TWO nodes per wave (half-wave each, 1 ch per
// lane), fp16 gathers (64 B/row).
// ---------------------------------------------------------------------------
template <bool DO_ELU>
__global__ __launch_bounds__(256) void k_gat32(
    const int* __restrict__ row_ptr, const uint16_t* __restrict__ csr_src,
    const _Float16* __restrict__ csr_ea,
    const _Float16* __restrict__ xs_h, const float* __restrict__ xd,
    const float* __restrict__ att, const float* __restrict__ bias,
    const float* __restrict__ We, float* __restrict__ hout, int n_nodes) {
  __shared__ _Float16 sea[4][2 * 32 * 8];
  int lane = threadIdx.x & 63;
  int wid = threadIdx.x >> 6;
  int half = lane >> 5;
  int hl = lane & 31;
  int node = blockIdx.x * 8 + wid * 2 + half;
  if (node >= n_nodes) return;
  int ch = hl;

  float xdv = xd[(size_t)node * 32 + ch];
  float attv = att[ch];
  h2v wh[4];
#pragma unroll
  for (int t = 0; t < 4; ++t) {
    wh[t][0] = (_Float16)We[(2 * t) * 32 + ch];
    wh[t][1] = (_Float16)We[(2 * t + 1) * 32 + ch];
  }

  float acc = 0.f, l_run = 0.f;
  int beg = row_ptr[node], end = row_ptr[node + 1];
  int deg = end - beg;
  int um = max(deg, __shfl_xor(deg, 32, 64));  // uniform max degree over wave

  for (int cb = 0; cb < um; cb += 32) {
    int cbeg = beg + cb;
    int cnt = min(end - cbeg, 32);  // may be <= 0 for this half
    int sv = (hl < cnt) ? (int)__builtin_nontemporal_load(csr_src + cbeg + hl) : 0;
    if (hl < cnt) {
      h8v t = __builtin_nontemporal_load((const h8v*)(csr_ea + (size_t)(cbeg + hl) * 8));
      *(h8v*)&sea[wid][half * 256 + hl * 8] = t;
    }

    auto gat_load = [&](int i) -> _Float16 {
      int idx = min(i, cnt - 1);
      idx = max(idx, 0);
      int s = __shfl(sv, half * 32 + idx, 64);
      return xs_h[(size_t)s * 32 + ch];
    };
    auto compute = [&](int i, _Float16 xh) {
      const _Float16* pe = &sea[wid][half * 256 + i * 8];
      h2v a0 = *(const h2v*)(pe);
      h2v a1 = *(const h2v*)(pe + 2);
      h2v a2 = *(const h2v*)(pe + 4);
      h2v a3 = *(const h2v*)(pe + 6);
      float e = dot2f(a3, wh[3], dot2f(a2, wh[2], dot2f(a1, wh[1], dot2f(a0, wh[0], 0.f))));
      float c = (float)xh;
      float z = c + xdv + e;
      z = fmaxf(z, kNegSlope * z);
      float sc = z * attv;
      sc += __shfl_xor(sc, 1, 64);
      sc += __shfl_xor(sc, 2, 64);
      sc += __shfl_xor(sc, 4, 64);
      sc += __shfl_xor(sc, 8, 64);
      sc += __shfl_xor(sc, 16, 64);  // head = 32 lanes within the half
      float p = (i < cnt) ? __expf(sc) : 0.f;
      l_run += p;
      acc += p * c;
    };

    int icnt = min(um - cb, 32);  // uniform inner bound
    _Float16 x0 = gat_load(0);
    _Float16 x1 = gat_load(1);
    int i = 0;
    for (; i + 2 <= icnt; i += 2) {
      _Float16 c0 = x0, c1 = x1;
      x0 = gat_load(i + 2);
      x1 = gat_load(i + 3);
      compute(i, c0);
      compute(i + 1, c1);
    }
    if (i < icnt) compute(i, x0);
  }

  float inv = (l_run > 0.f) ? (1.f / l_run) : 0.f;
  float o = acc * inv + bias[ch];
  if (DO_ELU) o = (o > 0.f) ? o : (__expf(o) - 1.f);
  __builtin_nontemporal_store(o, hout + (size_t)node * 32 + ch);
}

// ---------------------------------------------------------------------------
// Global mean-pool + 2-layer MLP.
// ---------------------------------------------------------------------------
__device__ inline int lowerb(const int* a, int n, int v) {
  int lo = 0, hi = n;
  while (lo < hi) {
    int mid = (lo + hi) >> 1;
    if (a[mid] < v) lo = mid + 1; else hi = mid;
  }
  return lo;
}

__global__ __launch_bounds__(64) void k_pool_mlp(
    const float* __restrict__ h3, const int* __restrict__ batch,
    const float* __restrict__ Wm1, const float* __restrict__ bm1,
    const float* __restrict__ Wm2, const float* __restrict__ bm2,
    float* __restrict__ out, int n_nodes) {
  int g = blockIdx.x;
  int t = threadIdx.x;
  int lo = lowerb(batch, n_nodes, g);
  int hi = lowerb(batch, n_nodes, g + 1);
  int c = t & 31, half = t >> 5;
  float sum = 0.f;
  for (int i = lo + half; i < hi; i += 2) sum += h3[(size_t)i * 32 + c];
  sum += __shfl_xor(sum, 32, 64);
  float cnt = (float)(hi - lo);
  float emb = sum / fmaxf(cnt, 1.f);
  __shared__ float sh_emb[32];
  __shared__ float sh_hid[64];
  if (half == 0) sh_emb[c] = emb;
  __syncthreads();
  float hv = bm1[t];
  for (int k = 0; k < 32; ++k) hv += sh_emb[k] * Wm1[k * 64 + t];
  hv = fmaxf(hv, 0.f);
  sh_hid[t] = hv;
  __syncthreads();
  float ov = bm2[t];
  for (int k = 0; k < 64; ++k) ov += sh_hid[k] * Wm2[k * 64 + t];
  out[(size_t)g * 64 + t] = ov;
}

// ---------------------------------------------------------------------------
extern "C" void kernel_launch(void* const* d_in, const int* in_sizes, int n_in,
                              void* d_out, int out_size, void* d_ws, size_t ws_size,
                              hipStream_t stream) {
  const float* x = (const float*)d_in[0];
  const int* esrc = (const int*)d_in[1];
  const int* edst = (const int*)d_in[2];
  const float* eattr = (const float*)d_in[3];
  const int* batch = (const int*)d_in[4];
  const float* W1s = (const float*)d_in[5];
  const float* W1d = (const float*)d_in[6];
  const float* W1e = (const float*)d_in[7];
  const float* b1s = (const float*)d_in[8];
  const float* b1d = (const float*)d_in[9];
  const float* att1 = (const float*)d_in[10];
  const float* bias1 = (const float*)d_in[11];
  const float* W2s = (const float*)d_in[12];
  const float* W2d = (const float*)d_in[13];
  const float* W2e = (const float*)d_in[14];
  const float* b2s = (const float*)d_in[15];
  const float* b2d = (const float*)d_in[16];
  const float* att2 = (const float*)d_in[17];
  const float* bias2 = (const float*)d_in[18];
  const float* W3s = (const float*)d_in[19];
  const float* W3d = (const float*)d_in[20];
  const float* W3e = (const float*)d_in[21];
  const float* b3s = (const float*)d_in[22];
  const float* b3d = (const float*)d_in[23];
  const float* att3 = (const float*)d_in[24];
  const float* bias3 = (const float*)d_in[25];
  const float* Wm1 = (const float*)d_in[26];
  const float* bm1 = (const float*)d_in[27];
  const float* Wm2 = (const float*)d_in[28];
  const float* bm2 = (const float*)d_in[29];

  constexpr int kNB = (kN + 255) / 256;

  char* p = (char*)d_ws;
  auto take = [&](size_t bytes) {
    char* r = p;
    p += (bytes + 255) & ~(size_t)255;
    return r;
  };
  int* row_ptr = (int*)take((size_t)(kN + 1) * sizeof(int));
  int* counts = (int*)take((size_t)kN * sizeof(int));
  int* fill = (int*)take((size_t)kN * sizeof(int));
  int* excl = (int*)take((size_t)kN * sizeof(int));
  int* bsums = (int*)take((size_t)kNB * sizeof(int));
  int* boff = (int*)take((size_t)kNB * sizeof(int));
  uint16_t* csr_src = (uint16_t*)take((size_t)kE * sizeof(uint16_t));
  _Float16* csr_ea = (_Float16*)take((size_t)kE * 8 * sizeof(_Float16));
  _Float16* xs_h = (_Float16*)take((size_t)kN * 128 * sizeof(_Float16));
  float* xd = (float*)take((size_t)kN * 128 * sizeof(float));
  float* hA = (float*)take((size_t)kN * 128 * sizeof(float));
  float* hB = (float*)take((size_t)kN * 128 * sizeof(float));

  hipMemsetAsync(counts, 0, (size_t)kN * sizeof(int), stream);
  hipMemsetAsync(fill, 0, (size_t)kN * sizeof(int), stream);

  k_hist<<<(kE + 255) / 256, 256, 0, stream>>>(edst, counts, kE);
  k_scan_blk<<<kNB, 256, 0, stream>>>(counts, excl, bsums, kN);
  k_scan_top<<<1, 256, 0, stream>>>(bsums, boff, row_ptr + kN, kNB);
  k_scan_add<<<kNB, 256, 0, stream>>>(excl, boff, row_ptr, kN);
  k_scatter<<<(kE + 255) / 256, 256, 0, stream>>>(esrc, edst, eattr, row_ptr, fill,
                                                  csr_src, csr_ea, kE);

  // Layer 1: in=16 -> H=4, C=32 (D=128), ELU
  k_transform<16, 128><<<kN / 16, 128, 0, stream>>>(x, W1s, b1s, W1d, b1d, xs_h, xd, kN);
  k_gat128<true><<<kN / 4, 256, 0, stream>>>(row_ptr, csr_src, csr_ea, xs_h, xd,
                                             att1, bias1, W1e, hA, kN);
  // Layer 2: in=128 -> D=128, ELU
  k_transform<128, 128><<<kN / 16, 128, 0, stream>>>(hA, W2s, b2s, W2d, b2d, xs_h, xd, kN);
  k_gat128<true><<<kN / 4, 256, 0, stream>>>(row_ptr, csr_src, csr_ea, xs_h, xd,
                                             att2, bias2, W2e, hB, kN);
  // Layer 3: in=128 -> H=1, C=32 (D=32), no ELU
  k_transform<128, 32><<<kN / 16, 128, 0, stream>>>(hB, W3s, b3s, W3d, b3d, xs_h, xd, kN);
  k_gat32<false><<<kN / 8, 256, 0, stream>>>(row_ptr, csr_src, csr_ea, xs_h, xd,
                                             att3, bias3, W3e, hA, kN);
  // Pool + MLP
  k_pool_mlp<<<kG, 64, 0, stream>>>(hA, batch, Wm1, bm1, Wm2, bm2, (float*)d_out, kN);
}

// Round 5
// 500.757 us; speedup vs baseline: 1.6090x; 1.1213x over previous
//
#include <hip/hip_runtime.h>
#include <cstdint>
#include <cstddef>

// Problem constants (fixed by the reference).
constexpr int kN = 50000;      // nodes  (< 65536 -> src ids fit in uint16)
constexpr int kE = 800000;     // edges
constexpr int kG = 512;        // graphs
constexpr float kNegSlope = 0.2f;

typedef float f4v __attribute__((ext_vector_type(4)));
typedef float f2v __attribute__((ext_vector_type(2)));
typedef _Float16 h2v __attribute__((ext_vector_type(2)));
typedef _Float16 h8v __attribute__((ext_vector_type(8)));

#if defined(__has_builtin)
#if __has_builtin(__builtin_amdgcn_fdot2)
#define HAS_FDOT2 1
#endif
#endif

__device__ inline float dot2f(h2v a, h2v b, float c) {
#ifdef HAS_FDOT2
  return __builtin_amdgcn_fdot2(a, b, c, false);
#else
  return c + (float)a.x * (float)b.x + (float)a.y * (float)b.y;
#endif
}

// ---------------------------------------------------------------------------
// CSR build: histogram of dst -> block-scan -> scatter (fp16 edge attrs,
// u16 src ids).
// ---------------------------------------------------------------------------
__global__ void k_hist(const int* __restrict__ dst, int* __restrict__ counts, int n) {
  int i = blockIdx.x * blockDim.x + threadIdx.x;
  if (i < n) atomicAdd(&counts[dst[i]], 1);
}

__global__ __launch_bounds__(256) void k_scan_blk(const int* __restrict__ counts,
                                                  int* __restrict__ excl,
                                                  int* __restrict__ bsums, int n) {
  __shared__ int sh[256];
  int tid = threadIdx.x;
  int i = blockIdx.x * 256 + tid;
  int c = (i < n) ? counts[i] : 0;
  sh[tid] = c;
  __syncthreads();
  for (int off = 1; off < 256; off <<= 1) {
    int t = (tid >= off) ? sh[tid - off] : 0;
    __syncthreads();
    sh[tid] += t;
    __syncthreads();
  }
  if (i < n) excl[i] = sh[tid] - c;
  if (tid == 255) bsums[blockIdx.x] = sh[255];
}

__global__ __launch_bounds__(256) void k_scan_top(const int* __restrict__ bsums,
                                                  int* __restrict__ boff,
                                                  int* __restrict__ row_ptr_last,
                                                  int nb) {
  __shared__ int sh[256];
  int tid = threadIdx.x;
  int c = (tid < nb) ? bsums[tid] : 0;
  sh[tid] = c;
  __syncthreads();
  for (int off = 1; off < 256; off <<= 1) {
    int t = (tid >= off) ? sh[tid - off] : 0;
    __syncthreads();
    sh[tid] += t;
    __syncthreads();
  }
  if (tid < nb) boff[tid] = sh[tid] - c;
  if (tid == 255) *row_ptr_last = sh[255];
}

__global__ __launch_bounds__(256) void k_scan_add(const int* __restrict__ excl,
                                                  const int* __restrict__ boff,
                                                  int* __restrict__ row_ptr, int n) {
  int i = blockIdx.x * 256 + threadIdx.x;
  if (i < n) row_ptr[i] = excl[i] + boff[blockIdx.x];
}

__global__ void k_scatter(const int* __restrict__ src, const int* __restrict__ dst,
                          const float* __restrict__ eattr,
                          const int* __restrict__ row_ptr, int* __restrict__ fill,
                          uint16_t* __restrict__ csr_src, _Float16* __restrict__ csr_ea,
                          int n) {
  int i = blockIdx.x * blockDim.x + threadIdx.x;
  if (i >= n) return;
  int d = dst[i];
  int p = row_ptr[d] + atomicAdd(&fill[d], 1);
  csr_src[p] = (uint16_t)src[i];
  const float4* s4 = (const float4*)eattr + (size_t)i * 2;
  float4 a = s4[0];
  float4 b = s4[1];
  h8v hv;
  hv[0] = (_Float16)a.x; hv[1] = (_Float16)a.y; hv[2] = (_Float16)a.z; hv[3] = (_Float16)a.w;
  hv[4] = (_Float16)b.x; hv[5] = (_Float16)b.y; hv[6] = (_Float16)b.z; hv[7] = (_Float16)b.w;
  *(h8v*)(csr_ea + (size_t)p * 8) = hv;
}

// ---------------------------------------------------------------------------
// Prep: cast node features x (fp32, K=16) to fp16 padded to K=32.
// ---------------------------------------------------------------------------
__global__ __launch_bounds__(256) void k_prep_x(const float* __restrict__ x,
                                                _Float16* __restrict__ xf, int n) {
  int i = blockIdx.x * 256 + threadIdx.x;   // over n*32
  if (i >= n * 32) return;
  int node = i >> 5, col = i & 31;
  xf[i] = (col < 16) ? (_Float16)x[node * 16 + col] : (_Float16)0.f;
}

// Prep: weights [IND x OUTD] (Ws then Wd) -> fp16 transposed Wt[(2*OUTD) x K],
// k-contiguous per output column, zero-padded to K.
__global__ __launch_bounds__(256) void k_prep_w(const float* __restrict__ Ws,
                                                const float* __restrict__ Wd,
                                                _Float16* __restrict__ Wt,
                                                int IND, int OUTD, int K) {
  int idx = blockIdx.x * 256 + threadIdx.x;  // over 2*OUTD*K
  if (idx >= 2 * OUTD * K) return;
  int c = idx / K, k = idx % K;
  const float* W = (c < OUTD) ? Ws : Wd;
  int cc = (c < OUTD) ? c : c - OUTD;
  Wt[idx] = (k < IND) ? (_Float16)W[(size_t)k * OUTD + cc] : (_Float16)0.f;
}

// ---------------------------------------------------------------------------
// MFMA node transform: [xs | xd] = h @ [Ws | Wd] + [bs | bd].
// h fp16 [n x K] (K = KT*32), Wt fp16 [(NC2*16) x K] transposed, MFMA
// 16x16x32_f16 with fp32 accumulate.  One wave per 16-node tile; no LDS.
// A-frag: m=lane&15, k=quad*8+j.  B-frag: n=lane&15, same k.
// C/D: col=lane&15, row=quad*4+reg  [per m89/m120 verified layouts].
// First NC2/2 col-chunks -> xs (fp16); rest -> xd (fp32).
// ---------------------------------------------------------------------------
template <int KT, int NC2>
__global__ __launch_bounds__(256) void k_tmfma(
    const _Float16* __restrict__ hf, const _Float16* __restrict__ Wt,
    const float* __restrict__ bs, const float* __restrict__ bd,
    _Float16* __restrict__ xs_h, float* __restrict__ xd, int n_nodes) {
  constexpr int K = KT * 32;
  constexpr int NCS = NC2 / 2;
  constexpr int D = NCS * 16;       // per-matrix output width
  int lane = threadIdx.x & 63;
  int wid = threadIdx.x >> 6;
  int m = lane & 15;
  int quad = lane >> 4;
  int base = (blockIdx.x * 4 + wid) * 16;
  if (base >= n_nodes) return;
  int arow = min(base + m, n_nodes - 1);

  h8v a[KT];
#pragma unroll
  for (int t = 0; t < KT; ++t)
    a[t] = *(const h8v*)(hf + (size_t)arow * K + t * 32 + quad * 8);

  bool full = (base + 16 <= n_nodes);
#pragma unroll
  for (int c = 0; c < NC2; ++c) {
    f4v acc = {0.f, 0.f, 0.f, 0.f};
#pragma unroll
    for (int t = 0; t < KT; ++t) {
      h8v b = *(const h8v*)(Wt + (size_t)(c * 16 + m) * K + t * 32 + quad * 8);
      acc = __builtin_amdgcn_mfma_f32_16x16x32_f16(a[t], b, acc, 0, 0, 0);
    }
    float bv = (c < NCS) ? bs[c * 16 + m] : bd[(c - NCS) * 16 + m];
#pragma unroll
    for (int r = 0; r < 4; ++r) {
      int node = base + quad * 4 + r;
      if (full || node < n_nodes) {
        if (c < NCS)
          xs_h[(size_t)node * D + c * 16 + m] = (_Float16)(acc[r] + bv);
        else
          xd[(size_t)node * D + (c - NCS) * 16 + m] = acc[r] + bv;
      }
    }
  }
}

// ---------------------------------------------------------------------------
// Fused GATv2, D=128 (H=4, C=32): one wave per dst node, whole wave per edge
// (lane holds channels 2*lane, 2*lane+1).  No-max softmax (scores bounded
// ~|6| << 88).  fp16 gathers, fp16 edge attrs staged via LDS, dot2 score
// math, fp32 accumulation.  Output h written fp16.
// ---------------------------------------------------------------------------
template <bool DO_ELU>
__global__ __launch_bounds__(256) void k_gat128(
    const int* __restrict__ row_ptr, const uint16_t* __restrict__ csr_src,
    const _Float16* __restrict__ csr_ea,
    const _Float16* __restrict__ xs_h, const float* __restrict__ xd,
    const float* __restrict__ att, const float* __restrict__ bias,
    const float* __restrict__ We, _Float16* __restrict__ hout, int n_nodes) {
  __shared__ _Float16 sea[4][64 * 8];
  int lane = threadIdx.x & 63;
  int wid = threadIdx.x >> 6;
  int node = blockIdx.x * 4 + wid;
  if (node >= n_nodes) return;
  int ch0 = lane * 2;

  float2 xdv = *(const float2*)(xd + (size_t)node * 128 + ch0);
  float2 attv = *(const float2*)(att + ch0);
  // We columns (ch0, ch0+1) as fp16 pairs over the 8 edge dims.
  h2v wh0[4], wh1[4];
#pragma unroll
  for (int t = 0; t < 4; ++t) {
    float2 wa = *(const float2*)(We + (2 * t) * 128 + ch0);
    float2 wb = *(const float2*)(We + (2 * t + 1) * 128 + ch0);
    wh0[t][0] = (_Float16)wa.x; wh0[t][1] = (_Float16)wb.x;
    wh1[t][0] = (_Float16)wa.y; wh1[t][1] = (_Float16)wb.y;
  }

  float acc0 = 0.f, acc1 = 0.f, l_run = 0.f;
  int beg = row_ptr[node], end = row_ptr[node + 1];

  for (int cbeg = beg; cbeg < end; cbeg += 64) {
    int cnt = min(end - cbeg, 64);
    int sv = (lane < cnt) ? (int)__builtin_nontemporal_load(csr_src + cbeg + lane) : 0;
    if (lane < cnt) {
      h8v t = __builtin_nontemporal_load((const h8v*)(csr_ea + (size_t)(cbeg + lane) * 8));
      *(h8v*)&sea[wid][lane * 8] = t;
    }

    auto gat_load = [&](int i) -> h2v {
      int idx = min(i, cnt - 1);
      idx = max(idx, 0);
      int s = __shfl(sv, idx, 64);
      return *(const h2v*)(xs_h + (size_t)s * 128 + ch0);
    };
    auto compute = [&](int i, h2v xh) {
      const _Float16* pe = &sea[wid][i * 8];
      h2v a0 = *(const h2v*)(pe);
      h2v a1 = *(const h2v*)(pe + 2);
      h2v a2 = *(const h2v*)(pe + 4);
      h2v a3 = *(const h2v*)(pe + 6);
      float e0 = dot2f(a3, wh0[3], dot2f(a2, wh0[2], dot2f(a1, wh0[1], dot2f(a0, wh0[0], 0.f))));
      float e1 = dot2f(a3, wh1[3], dot2f(a2, wh1[2], dot2f(a1, wh1[1], dot2f(a0, wh1[0], 0.f))));
      float cx = (float)xh.x, cy = (float)xh.y;
      float z0 = cx + xdv.x + e0;
      float z1 = cy + xdv.y + e1;
      z0 = fmaxf(z0, kNegSlope * z0);
      z1 = fmaxf(z1, kNegSlope * z1);
      float sc = z0 * attv.x + z1 * attv.y;
      sc += __shfl_xor(sc, 1, 64);
      sc += __shfl_xor(sc, 2, 64);
      sc += __shfl_xor(sc, 4, 64);
      sc += __shfl_xor(sc, 8, 64);   // head = 16 lanes (32 ch, 2/lane)
      float p = __expf(sc);
      l_run += p;
      acc0 += p * cx;
      acc1 += p * cy;
    };

    h2v x0 = gat_load(0);
    h2v x1 = gat_load(1);
    int i = 0;
    for (; i + 2 <= cnt; i += 2) {
      h2v c0 = x0, c1 = x1;
      x0 = gat_load(i + 2);
      x1 = gat_load(i + 3);
      compute(i, c0);
      compute(i + 1, c1);
    }
    if (i < cnt) compute(i, x0);
  }

  float inv = (l_run > 0.f) ? (1.f / l_run) : 0.f;
  float2 bv = *(const float2*)(bias + ch0);
  float o0 = acc0 * inv + bv.x;
  float o1 = acc1 * inv + bv.y;
  if (DO_ELU) {
    o0 = (o0 > 0.f) ? o0 : (__expf(o0) - 1.f);
    o1 = (o1 > 0.f) ? o1 : (__expf(o1) - 1.f);
  }
  h2v ov;
  ov.x = (_Float16)o0;
  ov.y = (_Float16)o1;
  __builtin_nontemporal_store(ov, (h2v*)(hout + (size_t)node * 128 + ch0));
}

// ---------------------------------------------------------------------------
// Fused GATv2, D=32 (H=1, C=32): TWO nodes per wave (half-wave each, 1 ch per
// lane), fp16 gathers.  Output h written fp16.
// ---------------------------------------------------------------------------
template <bool DO_ELU>
__global__ __launch_bounds__(256) void k_gat32(
    const int* __restrict__ row_ptr, const uint16_t* __restrict__ csr_src,
    const _Float16* __restrict__ csr_ea,
    const _Float16* __restrict__ xs_h, const float* __restrict__ xd,
    const float* __restrict__ att, const float* __restrict__ bias,
    const float* __restrict__ We, _Float16* __restrict__ hout, int n_nodes) {
  __shared__ _Float16 sea[4][2 * 32 * 8];
  int lane = threadIdx.x & 63;
  int wid = threadIdx.x >> 6;
  int half = lane >> 5;
  int hl = lane & 31;
  int node = blockIdx.x * 8 + wid * 2 + half;
  if (node >= n_nodes) return;
  int ch = hl;

  float xdv = xd[(size_t)node * 32 + ch];
  float attv = att[ch];
  h2v wh[4];
#pragma unroll
  for (int t = 0; t < 4; ++t) {
    wh[t][0] = (_Float16)We[(2 * t) * 32 + ch];
    wh[t][1] = (_Float16)We[(2 * t + 1) * 32 + ch];
  }

  float acc = 0.f, l_run = 0.f;
  int beg = row_ptr[node], end = row_ptr[node + 1];
  int deg = end - beg;
  int um = max(deg, __shfl_xor(deg, 32, 64));  // uniform max degree over wave

  for (int cb = 0; cb < um; cb += 32) {
    int cbeg = beg + cb;
    int cnt = min(end - cbeg, 32);  // may be <= 0 for this half
    int sv = (hl < cnt) ? (int)__builtin_nontemporal_load(csr_src + cbeg + hl) : 0;
    if (hl < cnt) {
      h8v t = __builtin_nontemporal_load((const h8v*)(csr_ea + (size_t)(cbeg + hl) * 8));
      *(h8v*)&sea[wid][half * 256 + hl * 8] = t;
    }

    auto gat_load = [&](int i) -> _Float16 {
      int idx = min(i, cnt - 1);
      idx = max(idx, 0);
      int s = __shfl(sv, half * 32 + idx, 64);
      return xs_h[(size_t)s * 32 + ch];
    };
    auto compute = [&](int i, _Float16 xh) {
      const _Float16* pe = &sea[wid][half * 256 + i * 8];
      h2v a0 = *(const h2v*)(pe);
      h2v a1 = *(const h2v*)(pe + 2);
      h2v a2 = *(const h2v*)(pe + 4);
      h2v a3 = *(const h2v*)(pe + 6);
      float e = dot2f(a3, wh[3], dot2f(a2, wh[2], dot2f(a1, wh[1], dot2f(a0, wh[0], 0.f))));
      float c = (float)xh;
      float z = c + xdv + e;
      z = fmaxf(z, kNegSlope * z);
      float sc = z * attv;
      sc += __shfl_xor(sc, 1, 64);
      sc += __shfl_xor(sc, 2, 64);
      sc += __shfl_xor(sc, 4, 64);
      sc += __shfl_xor(sc, 8, 64);
      sc += __shfl_xor(sc, 16, 64);  // head = 32 lanes within the half
      float p = (i < cnt) ? __expf(sc) : 0.f;
      l_run += p;
      acc += p * c;
    };

    int icnt = min(um - cb, 32);  // uniform inner bound
    _Float16 x0 = gat_load(0);
    _Float16 x1 = gat_load(1);
    int i = 0;
    for (; i + 2 <= icnt; i += 2) {
      _Float16 c0 = x0, c1 = x1;
      x0 = gat_load(i + 2);
      x1 = gat_load(i + 3);
      compute(i, c0);
      compute(i + 1, c1);
    }
    if (i < icnt) compute(i, x0);
  }

  float inv = (l_run > 0.f) ? (1.f / l_run) : 0.f;
  float o = acc * inv + bias[ch];
  if (DO_ELU) o = (o > 0.f) ? o : (__expf(o) - 1.f);
  __builtin_nontemporal_store((_Float16)o, hout + (size_t)node * 32 + ch);
}

// ---------------------------------------------------------------------------
// Global mean-pool (fp16 input) + 2-layer MLP.
// ---------------------------------------------------------------------------
__device__ inline int lowerb(const int* a, int n, int v) {
  int lo = 0, hi = n;
  while (lo < hi) {
    int mid = (lo + hi) >> 1;
    if (a[mid] < v) lo = mid + 1; else hi = mid;
  }
  return lo;
}

__global__ __launch_bounds__(64) void k_pool_mlp(
    const _Float16* __restrict__ h3, const int* __restrict__ batch,
    const float* __restrict__ Wm1, const float* __restrict__ bm1,
    const float* __restrict__ Wm2, const float* __restrict__ bm2,
    float* __restrict__ out, int n_nodes) {
  int g = blockIdx.x;
  int t = threadIdx.x;
  int lo = lowerb(batch, n_nodes, g);
  int hi = lowerb(batch, n_nodes, g + 1);
  int c = t & 31, half = t >> 5;
  float sum = 0.f;
  for (int i = lo + half; i < hi; i += 2) sum += (float)h3[(size_t)i * 32 + c];
  sum += __shfl_xor(sum, 32, 64);
  float cnt = (float)(hi - lo);
  float emb = sum / fmaxf(cnt, 1.f);
  __shared__ float sh_emb[32];
  __shared__ float sh_hid[64];
  if (half == 0) sh_emb[c] = emb;
  __syncthreads();
  float hv = bm1[t];
  for (int k = 0; k < 32; ++k) hv += sh_emb[k] * Wm1[k * 64 + t];
  hv = fmaxf(hv, 0.f);
  sh_hid[t] = hv;
  __syncthreads();
  float ov = bm2[t];
  for (int k = 0; k < 64; ++k) ov += sh_hid[k] * Wm2[k * 64 + t];
  out[(size_t)g * 64 + t] = ov;
}

// ---------------------------------------------------------------------------
extern "C" void kernel_launch(void* const* d_in, const int* in_sizes, int n_in,
                              void* d_out, int out_size, void* d_ws, size_t ws_size,
                              hipStream_t stream) {
  const float* x = (const float*)d_in[0];
  const int* esrc = (const int*)d_in[1];
  const int* edst = (const int*)d_in[2];
  const float* eattr = (const float*)d_in[3];
  const int* batch = (const int*)d_in[4];
  const float* W1s = (const float*)d_in[5];
  const float* W1d = (const float*)d_in[6];
  const float* W1e = (const float*)d_in[7];
  const float* b1s = (const float*)d_in[8];
  const float* b1d = (const float*)d_in[9];
  const float* att1 = (const float*)d_in[10];
  const float* bias1 = (const float*)d_in[11];
  const float* W2s = (const float*)d_in[12];
  const float* W2d = (const float*)d_in[13];
  const float* W2e = (const float*)d_in[14];
  const float* b2s = (const float*)d_in[15];
  const float* b2d = (const float*)d_in[16];
  const float* att2 = (const float*)d_in[17];
  const float* bias2 = (const float*)d_in[18];
  const float* W3s = (const float*)d_in[19];
  const float* W3d = (const float*)d_in[20];
  const float* W3e = (const float*)d_in[21];
  const float* b3s = (const float*)d_in[22];
  const float* b3d = (const float*)d_in[23];
  const float* att3 = (const float*)d_in[24];
  const float* bias3 = (const float*)d_in[25];
  const float* Wm1 = (const float*)d_in[26];
  const float* bm1 = (const float*)d_in[27];
  const float* Wm2 = (const float*)d_in[28];
  const float* bm2 = (const float*)d_in[29];

  constexpr int kNB = (kN + 255) / 256;

  char* p = (char*)d_ws;
  auto take = [&](size_t bytes) {
    char* r = p;
    p += (bytes + 255) & ~(size_t)255;
    return r;
  };
  int* row_ptr = (int*)take((size_t)(kN + 1) * sizeof(int));
  int* counts = (int*)take((size_t)kN * sizeof(int));
  int* fill = (int*)take((size_t)kN * sizeof(int));
  int* excl = (int*)take((size_t)kN * sizeof(int));
  int* bsums = (int*)take((size_t)kNB * sizeof(int));
  int* boff = (int*)take((size_t)kNB * sizeof(int));
  uint16_t* csr_src = (uint16_t*)take((size_t)kE * sizeof(uint16_t));
  _Float16* csr_ea = (_Float16*)take((size_t)kE * 8 * sizeof(_Float16));
  _Float16* xf = (_Float16*)take((size_t)kN * 32 * sizeof(_Float16));
  _Float16* Wt1 = (_Float16*)take((size_t)256 * 32 * sizeof(_Float16));
  _Float16* Wt2 = (_Float16*)take((size_t)256 * 128 * sizeof(_Float16));
  _Float16* Wt3 = (_Float16*)take((size_t)64 * 128 * sizeof(_Float16));
  _Float16* xs_h = (_Float16*)take((size_t)kN * 128 * sizeof(_Float16));
  float* xd = (float*)take((size_t)kN * 128 * sizeof(float));
  _Float16* hA = (_Float16*)take((size_t)kN * 128 * sizeof(_Float16));
  _Float16* hB = (_Float16*)take((size_t)kN * 128 * sizeof(_Float16));
  _Float16* h3 = (_Float16*)take((size_t)kN * 32 * sizeof(_Float16));

  hipMemsetAsync(counts, 0, (size_t)kN * sizeof(int), stream);
  hipMemsetAsync(fill, 0, (size_t)kN * sizeof(int), stream);

  // CSR build + weight/feature prep.
  k_hist<<<(kE + 255) / 256, 256, 0, stream>>>(edst, counts, kE);
  k_scan_blk<<<kNB, 256, 0, stream>>>(counts, excl, bsums, kN);
  k_scan_top<<<1, 256, 0, stream>>>(bsums, boff, row_ptr + kN, kNB);
  k_scan_add<<<kNB, 256, 0, stream>>>(excl, boff, row_ptr, kN);
  k_scatter<<<(kE + 255) / 256, 256, 0, stream>>>(esrc, edst, eattr, row_ptr, fill,
                                                  csr_src, csr_ea, kE);
  k_prep_x<<<(kN * 32 + 255) / 256, 256, 0, stream>>>(x, xf, kN);
  k_prep_w<<<(256 * 32 + 255) / 256, 256, 0, stream>>>(W1s, W1d, Wt1, 16, 128, 32);
  k_prep_w<<<(256 * 128 + 255) / 256, 256, 0, stream>>>(W2s, W2d, Wt2, 128, 128, 128);
  k_prep_w<<<(64 * 128 + 255) / 256, 256, 0, stream>>>(W3s, W3d, Wt3, 128, 32, 128);

  constexpr int kTB = (kN + 63) / 64;  // transform blocks (64 nodes each)

  // Layer 1: in=16(pad 32) -> D=128, ELU
  k_tmfma<1, 16><<<kTB, 256, 0, stream>>>(xf, Wt1, b1s, b1d, xs_h, xd, kN);
  k_gat128<true><<<kN / 4, 256, 0, stream>>>(row_ptr, csr_src, csr_ea, xs_h, xd,
                                             att1, bias1, W1e, hA, kN);
  // Layer 2: in=128 -> D=128, ELU
  k_tmfma<4, 16><<<kTB, 256, 0, stream>>>(hA, Wt2, b2s, b2d, xs_h, xd, kN);
  k_gat128<true><<<kN / 4, 256, 0, stream>>>(row_ptr, csr_src, csr_ea, xs_h, xd,
                                             att2, bias2, W2e, hB, kN);
  // Layer 3: in=128 -> D=32, no ELU
  k_tmfma<4, 4><<<kTB, 256, 0, stream>>>(hB, Wt3, b3s, b3d, xs_h, xd, kN);
  k_gat32<false><<<kN / 8, 256, 0, stream>>>(row_ptr, csr_src, csr_ea, xs_h, xd,
                                             att3, bias3, W3e, h3, kN);
  // Pool + MLP
  k_pool_mlp<<<kG, 64, 0, stream>>>(h3, batch, Wm1, bm1, Wm2, bm2, (float*)d_out, kN);
}

// Round 6
// 492.172 us; speedup vs baseline: 1.6371x; 1.0174x over previous
//
#include <hip/hip_runtime.h>
#include <cstdint>
#include <cstddef>

// Problem constants (fixed by the reference).
constexpr int kN = 50000;      // nodes  (< 65536 -> src ids fit in uint16)
constexpr int kE = 800000;     // edges
constexpr int kG = 512;        // graphs
constexpr float kNegSlope = 0.2f;

typedef float f4v __attribute__((ext_vector_type(4)));
typedef float f2v __attribute__((ext_vector_type(2)));
typedef _Float16 h2v __attribute__((ext_vector_type(2)));
typedef _Float16 h4v __attribute__((ext_vector_type(4)));
typedef _Float16 h8v __attribute__((ext_vector_type(8)));

#if defined(__has_builtin)
#if __has_builtin(__builtin_amdgcn_fdot2)
#define HAS_FDOT2 1
#endif
#endif

__device__ inline float dot2f(h2v a, h2v b, float c) {
#ifdef HAS_FDOT2
  return __builtin_amdgcn_fdot2(a, b, c, false);
#else
  return c + (float)a.x * (float)b.x + (float)a.y * (float)b.y;
#endif
}

// ---------------------------------------------------------------------------
// CSR build: histogram of dst -> block-scan -> scatter (fp16 edge attrs,
// u16 src ids).
// ---------------------------------------------------------------------------
__global__ void k_hist(const int* __restrict__ dst, int* __restrict__ counts, int n) {
  int i = blockIdx.x * blockDim.x + threadIdx.x;
  if (i < n) atomicAdd(&counts[dst[i]], 1);
}

__global__ __launch_bounds__(256) void k_scan_blk(const int* __restrict__ counts,
                                                  int* __restrict__ excl,
                                                  int* __restrict__ bsums, int n) {
  __shared__ int sh[256];
  int tid = threadIdx.x;
  int i = blockIdx.x * 256 + tid;
  int c = (i < n) ? counts[i] : 0;
  sh[tid] = c;
  __syncthreads();
  for (int off = 1; off < 256; off <<= 1) {
    int t = (tid >= off) ? sh[tid - off] : 0;
    __syncthreads();
    sh[tid] += t;
    __syncthreads();
  }
  if (i < n) excl[i] = sh[tid] - c;
  if (tid == 255) bsums[blockIdx.x] = sh[255];
}

__global__ __launch_bounds__(256) void k_scan_top(const int* __restrict__ bsums,
                                                  int* __restrict__ boff,
                                                  int* __restrict__ row_ptr_last,
                                                  int nb) {
  __shared__ int sh[256];
  int tid = threadIdx.x;
  int c = (tid < nb) ? bsums[tid] : 0;
  sh[tid] = c;
  __syncthreads();
  for (int off = 1; off < 256; off <<= 1) {
    int t = (tid >= off) ? sh[tid - off] : 0;
    __syncthreads();
    sh[tid] += t;
    __syncthreads();
  }
  if (tid < nb) boff[tid] = sh[tid] - c;
  if (tid == 255) *row_ptr_last = sh[255];
}

__global__ __launch_bounds__(256) void k_scan_add(const int* __restrict__ excl,
                                                  const int* __restrict__ boff,
                                                  int* __restrict__ row_ptr, int n) {
  int i = blockIdx.x * 256 + threadIdx.x;
  if (i < n) row_ptr[i] = excl[i] + boff[blockIdx.x];
}

__global__ void k_scatter(const int* __restrict__ src, const int* __restrict__ dst,
                          const float* __restrict__ eattr,
                          const int* __restrict__ row_ptr, int* __restrict__ fill,
                          uint16_t* __restrict__ csr_src, _Float16* __restrict__ csr_ea,
                          int n) {
  int i = blockIdx.x * blockDim.x + threadIdx.x;
  if (i >= n) return;
  int d = dst[i];
  int p = row_ptr[d] + atomicAdd(&fill[d], 1);
  csr_src[p] = (uint16_t)src[i];
  const float4* s4 = (const float4*)eattr + (size_t)i * 2;
  float4 a = s4[0];
  float4 b = s4[1];
  h8v hv;
  hv[0] = (_Float16)a.x; hv[1] = (_Float16)a.y; hv[2] = (_Float16)a.z; hv[3] = (_Float16)a.w;
  hv[4] = (_Float16)b.x; hv[5] = (_Float16)b.y; hv[6] = (_Float16)b.z; hv[7] = (_Float16)b.w;
  *(h8v*)(csr_ea + (size_t)p * 8) = hv;
}

// ---------------------------------------------------------------------------
// Fused prep: x -> fp16 padded K=32, and the three weight pairs -> fp16
// transposed (k-contiguous) zero-padded Wt buffers.  One launch.
// ---------------------------------------------------------------------------
__global__ __launch_bounds__(256) void k_prep(
    const float* __restrict__ x,
    const float* __restrict__ W1s, const float* __restrict__ W1d,
    const float* __restrict__ W2s, const float* __restrict__ W2d,
    const float* __restrict__ W3s, const float* __restrict__ W3d,
    _Float16* __restrict__ xf, _Float16* __restrict__ Wt1,
    _Float16* __restrict__ Wt2, _Float16* __restrict__ Wt3, int n) {
  int i = blockIdx.x * 256 + threadIdx.x;
  int r0 = n * 32;
  if (i < r0) {
    int node = i >> 5, col = i & 31;
    xf[i] = (col < 16) ? (_Float16)x[node * 16 + col] : (_Float16)0.f;
    return;
  }
  i -= r0;
  if (i < 256 * 32) {  // Wt1: 256 cols x K=32, IND=16, OUTD=128
    int c = i >> 5, k = i & 31;
    const float* W = (c < 128) ? W1s : W1d;
    Wt1[i] = (k < 16) ? (_Float16)W[k * 128 + (c & 127)] : (_Float16)0.f;
    return;
  }
  i -= 256 * 32;
  if (i < 256 * 128) {  // Wt2: 256 x 128, IND=128, OUTD=128
    int c = i >> 7, k = i & 127;
    const float* W = (c < 128) ? W2s : W2d;
    Wt2[i] = (_Float16)W[k * 128 + (c & 127)];
    return;
  }
  i -= 256 * 128;
  if (i < 64 * 128) {  // Wt3: 64 x 128, IND=128, OUTD=32
    int c = i >> 7, k = i & 127;
    const float* W = (c < 32) ? W3s : W3d;
    int cc = (c < 32) ? c : c - 32;
    Wt3[i] = (_Float16)W[k * 32 + cc];
  }
}

// ---------------------------------------------------------------------------
// MFMA node transform: [xs | xd] = h @ [Ws | Wd] + [bs | bd].
// (unchanged from R5 — verified correct + fast)
// ---------------------------------------------------------------------------
template <int KT, int NC2>
__global__ __launch_bounds__(256) void k_tmfma(
    const _Float16* __restrict__ hf, const _Float16* __restrict__ Wt,
    const float* __restrict__ bs, const float* __restrict__ bd,
    _Float16* __restrict__ xs_h, float* __restrict__ xd, int n_nodes) {
  constexpr int K = KT * 32;
  constexpr int NCS = NC2 / 2;
  constexpr int D = NCS * 16;
  int lane = threadIdx.x & 63;
  int wid = threadIdx.x >> 6;
  int m = lane & 15;
  int quad = lane >> 4;
  int base = (blockIdx.x * 4 + wid) * 16;
  if (base >= n_nodes) return;
  int arow = min(base + m, n_nodes - 1);

  h8v a[KT];
#pragma unroll
  for (int t = 0; t < KT; ++t)
    a[t] = *(const h8v*)(hf + (size_t)arow * K + t * 32 + quad * 8);

  bool full = (base + 16 <= n_nodes);
#pragma unroll
  for (int c = 0; c < NC2; ++c) {
    f4v acc = {0.f, 0.f, 0.f, 0.f};
#pragma unroll
    for (int t = 0; t < KT; ++t) {
      h8v b = *(const h8v*)(Wt + (size_t)(c * 16 + m) * K + t * 32 + quad * 8);
      acc = __builtin_amdgcn_mfma_f32_16x16x32_f16(a[t], b, acc, 0, 0, 0);
    }
    float bv = (c < NCS) ? bs[c * 16 + m] : bd[(c - NCS) * 16 + m];
#pragma unroll
    for (int r = 0; r < 4; ++r) {
      int node = base + quad * 4 + r;
      if (full || node < n_nodes) {
        if (c < NCS)
          xs_h[(size_t)node * D + c * 16 + m] = (_Float16)(acc[r] + bv);
        else
          xd[(size_t)node * D + (c - NCS) * 16 + m] = acc[r] + bv;
      }
    }
  }
}

// ---------------------------------------------------------------------------
// Fused GATv2, D=128 (H=4, C=32): one wave per dst node, TWO edge slots per
// wave (32 lanes/slot, 4 ch/lane).  Wave-uniform per-edge costs (reduction
// shuffles, exp, broadcast, loop) are amortized 2x vs whole-wave-per-edge.
// Chunked: 64 src ids preloaded coalesced, ea staged in LDS, 32-bit gather
// offsets, software pipeline depth 2 (4 edges in flight).
// ---------------------------------------------------------------------------
template <bool DO_ELU>
__global__ __launch_bounds__(256, 6) void k_gat128(
    const int* __restrict__ row_ptr, const uint16_t* __restrict__ csr_src,
    const _Float16* __restrict__ csr_ea,
    const _Float16* __restrict__ xs_h, const float* __restrict__ xd,
    const float* __restrict__ att, const float* __restrict__ bias,
    const float* __restrict__ We, _Float16* __restrict__ hout, int n_nodes) {
  __shared__ _Float16 sea[4][64 * 8];
  int lane = threadIdx.x & 63;
  int wid = threadIdx.x >> 6;
  int node = blockIdx.x * 4 + wid;
  if (node >= n_nodes) return;
  int slot = lane >> 5;   // 0 / 1
  int sl = lane & 31;
  int ch0 = sl * 4;       // this lane's 4 channels; head = sl>>3

  float4 xd4 = *(const float4*)(xd + (size_t)node * 128 + ch0);
  float4 at4 = *(const float4*)(att + ch0);
  float xdl[4] = {xd4.x, xd4.y, xd4.z, xd4.w};
  float atl[4] = {at4.x, at4.y, at4.z, at4.w};
  // We[k][ch0+c] as fp16 k-pairs: we[c][t] = {We[2t][ch0+c], We[2t+1][ch0+c]}
  h2v we[4][4];
  {
    float wr[8][4];
#pragma unroll
    for (int k = 0; k < 8; ++k) {
      float4 w = *(const float4*)(We + k * 128 + ch0);
      wr[k][0] = w.x; wr[k][1] = w.y; wr[k][2] = w.z; wr[k][3] = w.w;
    }
#pragma unroll
    for (int c = 0; c < 4; ++c)
#pragma unroll
      for (int t = 0; t < 4; ++t) {
        we[c][t][0] = (_Float16)wr[2 * t][c];
        we[c][t][1] = (_Float16)wr[2 * t + 1][c];
      }
  }

  float acc[4] = {0.f, 0.f, 0.f, 0.f};
  float l_run = 0.f;
  int beg = row_ptr[node], end = row_ptr[node + 1];
  const char* xsb = (const char*)xs_h;
  uint32_t chb = (uint32_t)sl * 8u;  // byte offset of this lane's 4 fp16 ch

  for (int cbeg = beg; cbeg < end; cbeg += 64) {
    int cnt = min(end - cbeg, 64);
    int sv = (lane < cnt) ? (int)__builtin_nontemporal_load(csr_src + cbeg + lane) : 0;
    if (lane < cnt) {
      h8v t = __builtin_nontemporal_load((const h8v*)(csr_ea + (size_t)(cbeg + lane) * 8));
      *(h8v*)&sea[wid][lane * 8] = t;
    }

    auto addr = [&](int i) -> uint32_t {
      int idx = min(i + slot, cnt - 1);
      int s = __shfl(sv, idx, 64);
      return (uint32_t)s * 256u + chb;
    };
    auto consume = [&](int i, h4v xh) {
      int e = i + slot;
      int ec = min(e, cnt - 1);
      const h2v* pe = (const h2v*)&sea[wid][ec * 8];
      h2v a0 = pe[0], a1 = pe[1], a2 = pe[2], a3 = pe[3];
      float xf[4];
#pragma unroll
      for (int c = 0; c < 4; ++c) xf[c] = (float)xh[c];
      float sc = 0.f;
#pragma unroll
      for (int c = 0; c < 4; ++c) {
        float ev = dot2f(a3, we[c][3],
                   dot2f(a2, we[c][2], dot2f(a1, we[c][1], dot2f(a0, we[c][0], 0.f))));
        float z = xf[c] + xdl[c] + ev;
        z = fmaxf(z, kNegSlope * z);
        sc = fmaf(z, atl[c], sc);
      }
      // head score: reduce over the 8 lanes covering this head's 32 channels
      sc += __shfl_xor(sc, 1, 64);
      sc += __shfl_xor(sc, 2, 64);
      sc += __shfl_xor(sc, 4, 64);
      float p = (e < cnt) ? __expf(sc) : 0.f;
      l_run += p;
#pragma unroll
      for (int c = 0; c < 4; ++c) acc[c] += p * xf[c];
    };

    uint32_t oa = addr(0), ob = addr(2);
    h4v xa = *(const h4v*)(xsb + oa);
    h4v xb = *(const h4v*)(xsb + ob);
    for (int i = 0; i < cnt; i += 4) {
      uint32_t na = addr(i + 4), nb = addr(i + 6);
      h4v pa = *(const h4v*)(xsb + na);
      h4v pb = *(const h4v*)(xsb + nb);
      consume(i, xa);
      consume(i + 2, xb);
      xa = pa;
      xb = pb;
    }
  }

  // combine the two slots
  l_run += __shfl_xor(l_run, 32, 64);
#pragma unroll
  for (int c = 0; c < 4; ++c) acc[c] += __shfl_xor(acc[c], 32, 64);

  if (slot == 0) {
    float inv = (l_run > 0.f) ? (1.f / l_run) : 0.f;
    float4 bv4 = *(const float4*)(bias + ch0);
    float bl[4] = {bv4.x, bv4.y, bv4.z, bv4.w};
    h4v ov;
#pragma unroll
    for (int c = 0; c < 4; ++c) {
      float o = acc[c] * inv + bl[c];
      if (DO_ELU) o = (o > 0.f) ? o : (__expf(o) - 1.f);
      ov[c] = (_Float16)o;
    }
    __builtin_nontemporal_store(ov, (h4v*)(hout + (size_t)node * 128 + ch0));
  }
}

// ---------------------------------------------------------------------------
// Fused GATv2, D=32 (H=1, C=32): one wave per dst node, EIGHT edge slots
// (8 lanes/slot, 4 ch/lane).  Chunk = 32 edges.
// ---------------------------------------------------------------------------
template <bool DO_ELU>
__global__ __launch_bounds__(256, 6) void k_gat32(
    const int* __restrict__ row_ptr, const uint16_t* __restrict__ csr_src,
    const _Float16* __restrict__ csr_ea,
    const _Float16* __restrict__ xs_h, const float* __restrict__ xd,
    const float* __restrict__ att, const float* __restrict__ bias,
    const float* __restrict__ We, _Float16* __restrict__ hout, int n_nodes) {
  __shared__ _Float16 sea[4][32 * 8];
  int lane = threadIdx.x & 63;
  int wid = threadIdx.x >> 6;
  int node = blockIdx.x * 4 + wid;
  if (node >= n_nodes) return;
  int slot = lane >> 3;   // 0..7
  int sl = lane & 7;
  int ch0 = sl * 4;

  float4 xd4 = *(const float4*)(xd + (size_t)node * 32 + ch0);
  float4 at4 = *(const float4*)(att + ch0);
  float xdl[4] = {xd4.x, xd4.y, xd4.z, xd4.w};
  float atl[4] = {at4.x, at4.y, at4.z, at4.w};
  h2v we[4][4];
  {
    float wr[8][4];
#pragma unroll
    for (int k = 0; k < 8; ++k) {
      float4 w = *(const float4*)(We + k * 32 + ch0);
      wr[k][0] = w.x; wr[k][1] = w.y; wr[k][2] = w.z; wr[k][3] = w.w;
    }
#pragma unroll
    for (int c = 0; c < 4; ++c)
#pragma unroll
      for (int t = 0; t < 4; ++t) {
        we[c][t][0] = (_Float16)wr[2 * t][c];
        we[c][t][1] = (_Float16)wr[2 * t + 1][c];
      }
  }

  float acc[4] = {0.f, 0.f, 0.f, 0.f};
  float l_run = 0.f;
  int beg = row_ptr[node], end = row_ptr[node + 1];
  const char* xsb = (const char*)xs_h;
  uint32_t chb = (uint32_t)sl * 8u;

  for (int cbeg = beg; cbeg < end; cbeg += 32) {
    int cnt = min(end - cbeg, 32);
    int sv = (lane < cnt) ? (int)__builtin_nontemporal_load(csr_src + cbeg + lane) : 0;
    if (lane < cnt) {
      h8v t = __builtin_nontemporal_load((const h8v*)(csr_ea + (size_t)(cbeg + lane) * 8));
      *(h8v*)&sea[wid][lane * 8] = t;
    }

    auto addr = [&](int i) -> uint32_t {
      int idx = min(i + slot, cnt - 1);
      int s = __shfl(sv, idx, 64);
      return (uint32_t)s * 64u + chb;
    };
    auto consume = [&](int i, h4v xh) {
      int e = i + slot;
      int ec = min(e, cnt - 1);
      const h2v* pe = (const h2v*)&sea[wid][ec * 8];
      h2v a0 = pe[0], a1 = pe[1], a2 = pe[2], a3 = pe[3];
      float xf[4];
#pragma unroll
      for (int c = 0; c < 4; ++c) xf[c] = (float)xh[c];
      float sc = 0.f;
#pragma unroll
      for (int c = 0; c < 4; ++c) {
        float ev = dot2f(a3, we[c][3],
                   dot2f(a2, we[c][2], dot2f(a1, we[c][1], dot2f(a0, we[c][0], 0.f))));
        float z = xf[c] + xdl[c] + ev;
        z = fmaxf(z, kNegSlope * z);
        sc = fmaf(z, atl[c], sc);
      }
      sc += __shfl_xor(sc, 1, 64);
      sc += __shfl_xor(sc, 2, 64);
      sc += __shfl_xor(sc, 4, 64);
      float p = (e < cnt) ? __expf(sc) : 0.f;
      l_run += p;
#pragma unroll
      for (int c = 0; c < 4; ++c) acc[c] += p * xf[c];
    };

    uint32_t oa = addr(0), ob = addr(8);
    h4v xa = *(const h4v*)(xsb + oa);
    h4v xb = *(const h4v*)(xsb + ob);
    for (int i = 0; i < cnt; i += 16) {
      uint32_t na = addr(i + 16), nb = addr(i + 24);
      h4v pa = *(const h4v*)(xsb + na);
      h4v pb = *(const h4v*)(xsb + nb);
      consume(i, xa);
      consume(i + 8, xb);
      xa = pa;
      xb = pb;
    }
  }

  // combine the 8 slots (lanes with equal sl)
#pragma unroll
  for (int off = 8; off < 64; off <<= 1) {
    l_run += __shfl_xor(l_run, off, 64);
#pragma unroll
    for (int c = 0; c < 4; ++c) acc[c] += __shfl_xor(acc[c], off, 64);
  }

  if (slot == 0) {
    float inv = (l_run > 0.f) ? (1.f / l_run) : 0.f;
    float4 bv4 = *(const float4*)(bias + ch0);
    float bl[4] = {bv4.x, bv4.y, bv4.z, bv4.w};
    h4v ov;
#pragma unroll
    for (int c = 0; c < 4; ++c) {
      float o = acc[c] * inv + bl[c];
      if (DO_ELU) o = (o > 0.f) ? o : (__expf(o) - 1.f);
      ov[c] = (_Float16)o;
    }
    __builtin_nontemporal_store(ov, (h4v*)(hout + (size_t)node * 32 + ch0));
  }
}

// ---------------------------------------------------------------------------
// Global mean-pool (fp16 input) + 2-layer MLP.
// ---------------------------------------------------------------------------
__device__ inline int lowerb(const int* a, int n, int v) {
  int lo = 0, hi = n;
  while (lo < hi) {
    int mid = (lo + hi) >> 1;
    if (a[mid] < v) lo = mid + 1; else hi = mid;
  }
  return lo;
}

__global__ __launch_bounds__(64) void k_pool_mlp(
    const _Float16* __restrict__ h3, const int* __restrict__ batch,
    const float* __restrict__ Wm1, const float* __restrict__ bm1,
    const float* __restrict__ Wm2, const float* __restrict__ bm2,
    float* __restrict__ out, int n_nodes) {
  int g = blockIdx.x;
  int t = threadIdx.x;
  int lo = lowerb(batch, n_nodes, g);
  int hi = lowerb(batch, n_nodes, g + 1);
  int c = t & 31, half = t >> 5;
  float sum = 0.f;
  for (int i = lo + half; i < hi; i += 2) sum += (float)h3[(size_t)i * 32 + c];
  sum += __shfl_xor(sum, 32, 64);
  float cnt = (float)(hi - lo);
  float emb = sum / fmaxf(cnt, 1.f);
  __shared__ float sh_emb[32];
  __shared__ float sh_hid[64];
  if (half == 0) sh_emb[c] = emb;
  __syncthreads();
  float hv = bm1[t];
  for (int k = 0; k < 32; ++k) hv += sh_emb[k] * Wm1[k * 64 + t];
  hv = fmaxf(hv, 0.f);
  sh_hid[t] = hv;
  __syncthreads();
  float ov = bm2[t];
  for (int k = 0; k < 64; ++k) ov += sh_hid[k] * Wm2[k * 64 + t];
  out[(size_t)g * 64 + t] = ov;
}

// ---------------------------------------------------------------------------
extern "C" void kernel_launch(void* const* d_in, const int* in_sizes, int n_in,
                              void* d_out, int out_size, void* d_ws, size_t ws_size,
                              hipStream_t stream) {
  const float* x = (const float*)d_in[0];
  const int* esrc = (const int*)d_in[1];
  const int* edst = (const int*)d_in[2];
  const float* eattr = (const float*)d_in[3];
  const int* batch = (const int*)d_in[4];
  const float* W1s = (const float*)d_in[5];
  const float* W1d = (const float*)d_in[6];
  const float* W1e = (const float*)d_in[7];
  const float* b1s = (const float*)d_in[8];
  const float* b1d = (const float*)d_in[9];
  const float* att1 = (const float*)d_in[10];
  const float* bias1 = (const float*)d_in[11];
  const float* W2s = (const float*)d_in[12];
  const float* W2d = (const float*)d_in[13];
  const float* W2e = (const float*)d_in[14];
  const float* b2s = (const float*)d_in[15];
  const float* b2d = (const float*)d_in[16];
  const float* att2 = (const float*)d_in[17];
  const float* bias2 = (const float*)d_in[18];
  const float* W3s = (const float*)d_in[19];
  const float* W3d = (const float*)d_in[20];
  const float* W3e = (const float*)d_in[21];
  const float* b3s = (const float*)d_in[22];
  const float* b3d = (const float*)d_in[23];
  const float* att3 = (const float*)d_in[24];
  const float* bias3 = (const float*)d_in[25];
  const float* Wm1 = (const float*)d_in[26];
  const float* bm1 = (const float*)d_in[27];
  const float* Wm2 = (const float*)d_in[28];
  const float* bm2 = (const float*)d_in[29];

  constexpr int kNB = (kN + 255) / 256;

  char* p = (char*)d_ws;
  auto take = [&](size_t bytes) {
    char* r = p;
    p += (bytes + 255) & ~(size_t)255;
    return r;
  };
  constexpr size_t kCntB = ((size_t)kN * sizeof(int) + 255) & ~(size_t)255;
  int* row_ptr = (int*)take((size_t)(kN + 1) * sizeof(int));
  char* zero2 = take(2 * kCntB);            // counts + fill, one memset
  int* counts = (int*)zero2;
  int* fill = (int*)(zero2 + kCntB);
  int* excl = (int*)take((size_t)kN * sizeof(int));
  int* bsums = (int*)take((size_t)kNB * sizeof(int));
  int* boff = (int*)take((size_t)kNB * sizeof(int));
  uint16_t* csr_src = (uint16_t*)take((size_t)kE * sizeof(uint16_t));
  _Float16* csr_ea = (_Float16*)take((size_t)kE * 8 * sizeof(_Float16));
  _Float16* xf = (_Float16*)take((size_t)kN * 32 * sizeof(_Float16));
  _Float16* Wt1 = (_Float16*)take((size_t)256 * 32 * sizeof(_Float16));
  _Float16* Wt2 = (_Float16*)take((size_t)256 * 128 * sizeof(_Float16));
  _Float16* Wt3 = (_Float16*)take((size_t)64 * 128 * sizeof(_Float16));
  _Float16* xs_h = (_Float16*)take((size_t)kN * 128 * sizeof(_Float16));
  float* xd = (float*)take((size_t)kN * 128 * sizeof(float));
  _Float16* hA = (_Float16*)take((size_t)kN * 128 * sizeof(_Float16));
  _Float16* hB = (_Float16*)take((size_t)kN * 128 * sizeof(_Float16));
  _Float16* h3 = (_Float16*)take((size_t)kN * 32 * sizeof(_Float16));

  hipMemsetAsync(zero2, 0, 2 * kCntB, stream);

  // CSR build + fused prep.
  k_hist<<<(kE + 255) / 256, 256, 0, stream>>>(edst, counts, kE);
  k_scan_blk<<<kNB, 256, 0, stream>>>(counts, excl, bsums, kN);
  k_scan_top<<<1, 256, 0, stream>>>(bsums, boff, row_ptr + kN, kNB);
  k_scan_add<<<kNB, 256, 0, stream>>>(excl, boff, row_ptr, kN);
  k_scatter<<<(kE + 255) / 256, 256, 0, stream>>>(esrc, edst, eattr, row_ptr, fill,
                                                  csr_src, csr_ea, kE);
  {
    int prep_total = kN * 32 + 256 * 32 + 256 * 128 + 64 * 128;
    k_prep<<<(prep_total + 255) / 256, 256, 0, stream>>>(
        x, W1s, W1d, W2s, W2d, W3s, W3d, xf, Wt1, Wt2, Wt3, kN);
  }

  constexpr int kTB = (kN + 63) / 64;  // transform blocks (64 nodes each)

  // Layer 1: in=16(pad 32) -> D=128, ELU
  k_tmfma<1, 16><<<kTB, 256, 0, stream>>>(xf, Wt1, b1s, b1d, xs_h, xd, kN);
  k_gat128<true><<<(kN + 3) / 4, 256, 0, stream>>>(row_ptr, csr_src, csr_ea, xs_h, xd,
                                                   att1, bias1, W1e, hA, kN);
  // Layer 2: in=128 -> D=128, ELU
  k_tmfma<4, 16><<<kTB, 256, 0, stream>>>(hA, Wt2, b2s, b2d, xs_h, xd, kN);
  k_gat128<true><<<(kN + 3) / 4, 256, 0, stream>>>(row_ptr, csr_src, csr_ea, xs_h, xd,
                                                   att2, bias2, W2e, hB, kN);
  // Layer 3: in=128 -> D=32, no ELU
  k_tmfma<4, 4><<<kTB, 256, 0, stream>>>(hB, Wt3, b3s, b3d, xs_h, xd, kN);
  k_gat32<false><<<(kN + 3) / 4, 256, 0, stream>>>(row_ptr, csr_src, csr_ea, xs_h, xd,
                                                   att3, bias3, W3e, h3, kN);
  // Pool + MLP
  k_pool_mlp<<<kG, 64, 0, stream>>>(h3, batch, Wm1, bm1, Wm2, bm2, (float*)d_out, kN);
}